// Round 1
// baseline (2276.165 us; speedup 1.0000x reference)
//
#include <hip/hip_runtime.h>

#define BB 1024
#define VV 6890
#define NJ 24
#define NBETA 10
#define PF 207          // (J-1)*9
#define V3 (VV*3)       // 20670

__device__ __constant__ int kParents[NJ] = {-1,0,0,0,1,2,3,4,5,6,7,8,9,9,9,12,13,14,16,17,18,19,20,21};

// ---------------------------------------------------------------------------
// Kernel 1: precompute Jt = Jreg @ v_template  (24,3)
//           and      Jsd = Jreg @ shapedirs    (24,3,10)
// One block per joint j, 256 threads, strided partial sums + reduce.
// ---------------------------------------------------------------------------
__global__ __launch_bounds__(256) void k_jreg(
    const float* __restrict__ Jreg,      // (24, V)
    const float* __restrict__ vtemp,     // (V, 3)
    const float* __restrict__ sdirs,     // (V, 3, 10)
    float* __restrict__ Jsd,             // (24, 3, 10) ws
    float* __restrict__ Jt)              // (24, 3) ws
{
    int j = blockIdx.x;
    int tid = threadIdx.x;
    float acc[33];
#pragma unroll
    for (int i = 0; i < 33; ++i) acc[i] = 0.f;

    for (int v = tid; v < VV; v += 256) {
        float w = Jreg[j * VV + v];
#pragma unroll
        for (int c = 0; c < 3; ++c) {
            acc[30 + c] += w * vtemp[v * 3 + c];
#pragma unroll
            for (int l = 0; l < NBETA; ++l)
                acc[c * NBETA + l] += w * sdirs[(v * 3 + c) * NBETA + l];
        }
    }

    // wave reduce (64-lane)
#pragma unroll
    for (int i = 0; i < 33; ++i) {
        float x = acc[i];
        for (int off = 32; off > 0; off >>= 1) x += __shfl_down(x, off);
        acc[i] = x;
    }
    __shared__ float sred[33][4];
    int wave = tid >> 6, lane = tid & 63;
    if (lane == 0) {
#pragma unroll
        for (int i = 0; i < 33; ++i) sred[i][wave] = acc[i];
    }
    __syncthreads();
    if (tid == 0) {
#pragma unroll
        for (int i = 0; i < 33; ++i) {
            float s = sred[i][0] + sred[i][1] + sred[i][2] + sred[i][3];
            if (i < 30) Jsd[j * 30 + i] = s;
            else        Jt[j * 3 + (i - 30)] = s;
        }
    }
}

// ---------------------------------------------------------------------------
// Kernel 2: per-batch — rodrigues, joints, kinematic chain, rel transforms,
// pose_feature, posed joints (+transl) to d_out.
// One thread per batch, 32 threads/block, chain stored in LDS per-lane.
// ---------------------------------------------------------------------------
__global__ __launch_bounds__(32) void k_batch(
    const float* __restrict__ transl,    // (B,3)
    const float* __restrict__ orient,    // (B,3)
    const float* __restrict__ betas,     // (B,10)
    const float* __restrict__ bpose,     // (B,69)
    const float* __restrict__ Jsd,       // (24,3,10)
    const float* __restrict__ Jt,        // (24,3)
    float* __restrict__ pfeat,           // (B,207) ws
    float* __restrict__ relt,            // (B,24,12) ws
    float* __restrict__ joints_out)      // (B,24,3) at d_out + B*V*3
{
    int t = threadIdx.x;
    int b = blockIdx.x * 32 + t;

    __shared__ float chain[NJ][12][32];

    float bet[NBETA];
#pragma unroll
    for (int l = 0; l < NBETA; ++l) bet[l] = betas[b * NBETA + l];

    float jx[NJ], jy[NJ], jz[NJ];
#pragma unroll
    for (int j = 0; j < NJ; ++j) {
        float a = Jt[j * 3 + 0], bb = Jt[j * 3 + 1], cc = Jt[j * 3 + 2];
#pragma unroll
        for (int l = 0; l < NBETA; ++l) {
            a  += Jsd[j * 30 + 0 * NBETA + l] * bet[l];
            bb += Jsd[j * 30 + 1 * NBETA + l] * bet[l];
            cc += Jsd[j * 30 + 2 * NBETA + l] * bet[l];
        }
        jx[j] = a; jy[j] = bb; jz[j] = cc;
    }

    float tr0 = transl[b * 3 + 0], tr1 = transl[b * 3 + 1], tr2 = transl[b * 3 + 2];

    for (int j = 0; j < NJ; ++j) {
        float rx, ry, rz;
        if (j == 0) {
            rx = orient[b * 3 + 0]; ry = orient[b * 3 + 1]; rz = orient[b * 3 + 2];
        } else {
            rx = bpose[b * 69 + (j - 1) * 3 + 0];
            ry = bpose[b * 69 + (j - 1) * 3 + 1];
            rz = bpose[b * 69 + (j - 1) * 3 + 2];
        }
        // rodrigues (matches ref: angle = ||r + 1e-8||, axis = r / angle)
        float ax = rx + 1e-8f, ay = ry + 1e-8f, az = rz + 1e-8f;
        float angle = sqrtf(ax * ax + ay * ay + az * az);
        float inv = 1.f / angle;
        float kx = rx * inv, ky = ry * inv, kz = rz * inv;
        float s = sinf(angle), c = cosf(angle), omc = 1.f - c;
        float R[9];
        R[0] = 1.f - omc * (ky * ky + kz * kz);
        R[1] = -s * kz + omc * (kx * ky);
        R[2] =  s * ky + omc * (kx * kz);
        R[3] =  s * kz + omc * (kx * ky);
        R[4] = 1.f - omc * (kx * kx + kz * kz);
        R[5] = -s * kx + omc * (ky * kz);
        R[6] = -s * ky + omc * (kx * kz);
        R[7] =  s * kx + omc * (ky * kz);
        R[8] = 1.f - omc * (kx * kx + ky * ky);

        if (j > 0) {
#pragma unroll
            for (int e = 0; e < 9; ++e) {
                float val = R[e] - ((e == 0 || e == 4 || e == 8) ? 1.f : 0.f);
                pfeat[b * PF + (j - 1) * 9 + e] = val;
            }
        }

        int p = kParents[j];
        float tx, ty, tz;
        if (j == 0) { tx = jx[0]; ty = jy[0]; tz = jz[0]; }
        else        { tx = jx[j] - jx[p]; ty = jy[j] - jy[p]; tz = jz[j] - jz[p]; }

        float A[12];
        if (j == 0) {
            A[0] = R[0]; A[1] = R[1]; A[2]  = R[2]; A[3]  = tx;
            A[4] = R[3]; A[5] = R[4]; A[6]  = R[5]; A[7]  = ty;
            A[8] = R[6]; A[9] = R[7]; A[10] = R[8]; A[11] = tz;
        } else {
            float P[12];
#pragma unroll
            for (int e = 0; e < 12; ++e) P[e] = chain[p][e][t];
#pragma unroll
            for (int r = 0; r < 3; ++r) {
#pragma unroll
                for (int cc = 0; cc < 3; ++cc)
                    A[r * 4 + cc] = P[r * 4 + 0] * R[0 * 3 + cc] +
                                    P[r * 4 + 1] * R[1 * 3 + cc] +
                                    P[r * 4 + 2] * R[2 * 3 + cc];
                A[r * 4 + 3] = P[r * 4 + 0] * tx + P[r * 4 + 1] * ty +
                               P[r * 4 + 2] * tz + P[r * 4 + 3];
            }
        }
#pragma unroll
        for (int e = 0; e < 12; ++e) chain[j][e][t] = A[e];

        joints_out[(b * NJ + j) * 3 + 0] = A[3]  + tr0;
        joints_out[(b * NJ + j) * 3 + 1] = A[7]  + tr1;
        joints_out[(b * NJ + j) * 3 + 2] = A[11] + tr2;

        float bx = A[0] * jx[j] + A[1] * jy[j] + A[2]  * jz[j];
        float by = A[4] * jx[j] + A[5] * jy[j] + A[6]  * jz[j];
        float bz = A[8] * jx[j] + A[9] * jy[j] + A[10] * jz[j];
        float* rt = relt + (b * NJ + j) * 12;
        rt[0] = A[0]; rt[1] = A[1]; rt[2]  = A[2];  rt[3]  = A[3]  - bx;
        rt[4] = A[4]; rt[5] = A[5]; rt[6]  = A[6];  rt[7]  = A[7]  - by;
        rt[8] = A[8]; rt[9] = A[9]; rt[10] = A[10]; rt[11] = A[11] - bz;
    }
}

// ---------------------------------------------------------------------------
// Kernel 3: fused vertex kernel. One block = one batch × 256 vertices.
// v_shaped + pose_offsets + LBS blend + affine + transl.
// ---------------------------------------------------------------------------
__global__ __launch_bounds__(256) void k_verts(
    const float* __restrict__ vtemp,     // (V,3)
    const float* __restrict__ sdirs,     // (V,3,10)
    const float* __restrict__ pdirs,     // (207, V*3)
    const float* __restrict__ lbsw,      // (V,24)
    const float* __restrict__ betas,     // (B,10)
    const float* __restrict__ transl,    // (B,3)
    const float* __restrict__ pfeat,     // (B,207)
    const float* __restrict__ relt,      // (B,24,12)
    float* __restrict__ verts)           // (B,V,3)
{
    int b = blockIdx.y;
    int t = threadIdx.x;
    int v = blockIdx.x * 256 + t;

    __shared__ float s_pf[PF];
    __shared__ float s_rel[NJ * 12];
    __shared__ float s_bet[NBETA];
    __shared__ float s_tr[3];

    if (t < PF) s_pf[t] = pfeat[b * PF + t];
    for (int i = t; i < NJ * 12; i += 256) s_rel[i] = relt[b * NJ * 12 + i];
    if (t < NBETA) s_bet[t] = betas[b * NBETA + t];
    if (t >= 32 && t < 35) s_tr[t - 32] = transl[b * 3 + (t - 32)];
    __syncthreads();

    if (v >= VV) return;

    // v_shaped
    float vp0 = vtemp[v * 3 + 0];
    float vp1 = vtemp[v * 3 + 1];
    float vp2 = vtemp[v * 3 + 2];
#pragma unroll
    for (int l = 0; l < NBETA; ++l) {
        float be = s_bet[l];
        vp0 += sdirs[(v * 3 + 0) * NBETA + l] * be;
        vp1 += sdirs[(v * 3 + 1) * NBETA + l] * be;
        vp2 += sdirs[(v * 3 + 2) * NBETA + l] * be;
    }

    // pose offsets: sum_k pf[k] * posedirs[k, v*3 + c]
    const float* pd = pdirs + v * 3;
    float p0 = 0.f, p1 = 0.f, p2 = 0.f;
#pragma unroll 9
    for (int k = 0; k < PF; ++k) {
        float f = s_pf[k];
        p0 += f * pd[(size_t)k * V3 + 0];
        p1 += f * pd[(size_t)k * V3 + 1];
        p2 += f * pd[(size_t)k * V3 + 2];
    }
    vp0 += p0; vp1 += p1; vp2 += p2;

    // LBS blend: T = sum_j w[v,j] * rel[b,j]  (3x4 affine)
    float T[12];
#pragma unroll
    for (int e = 0; e < 12; ++e) T[e] = 0.f;
#pragma unroll
    for (int j = 0; j < NJ; ++j) {
        float w = lbsw[v * NJ + j];
#pragma unroll
        for (int e = 0; e < 12; ++e) T[e] += w * s_rel[j * 12 + e];
    }

    float o0 = T[0] * vp0 + T[1] * vp1 + T[2]  * vp2 + T[3]  + s_tr[0];
    float o1 = T[4] * vp0 + T[5] * vp1 + T[6]  * vp2 + T[7]  + s_tr[1];
    float o2 = T[8] * vp0 + T[9] * vp1 + T[10] * vp2 + T[11] + s_tr[2];

    float* o = verts + ((size_t)b * VV + v) * 3;
    o[0] = o0; o[1] = o1; o[2] = o2;
}

extern "C" void kernel_launch(void* const* d_in, const int* in_sizes, int n_in,
                              void* d_out, int out_size, void* d_ws, size_t ws_size,
                              hipStream_t stream) {
    const float* transl = (const float*)d_in[0];
    const float* orient = (const float*)d_in[1];
    const float* betas  = (const float*)d_in[2];
    const float* bpose  = (const float*)d_in[3];
    const float* vtemp  = (const float*)d_in[4];
    const float* sdirs  = (const float*)d_in[5];
    const float* pdirs  = (const float*)d_in[6];
    const float* jreg   = (const float*)d_in[7];
    const float* lbsw   = (const float*)d_in[8];
    // d_in[9] = parents (hardcoded: SMPL topology)

    float* out = (float*)d_out;
    float* verts_out  = out;
    float* joints_out = out + (size_t)BB * VV * 3;

    float* ws    = (float*)d_ws;
    float* Jsd   = ws;                         // 720
    float* Jt    = ws + 720;                   // 72
    float* pfeat = ws + 792;                   // B*207
    float* relt  = ws + 792 + (size_t)BB * PF; // B*288

    k_jreg<<<NJ, 256, 0, stream>>>(jreg, vtemp, sdirs, Jsd, Jt);
    k_batch<<<BB / 32, 32, 0, stream>>>(transl, orient, betas, bpose,
                                        Jsd, Jt, pfeat, relt, joints_out);
    dim3 g((VV + 255) / 256, BB);
    k_verts<<<g, 256, 0, stream>>>(vtemp, sdirs, pdirs, lbsw, betas, transl,
                                   pfeat, relt, verts_out);
}

// Round 2
// 338.344 us; speedup vs baseline: 6.7274x; 6.7274x over previous
//
#include <hip/hip_runtime.h>

#define BB 1024
#define VV 6890
#define NJ 24
#define NBETA 10
#define PF 207          // (J-1)*9
#define V3 (VV*3)       // 20670
#define TB 16           // batches per block in k_verts

__device__ __constant__ int kParents[NJ] = {-1,0,0,0,1,2,3,4,5,6,7,8,9,9,9,12,13,14,16,17,18,19,20,21};

// ---------------------------------------------------------------------------
// Kernel 1: precompute Jt = Jreg @ v_template  (24,3)
//           and      Jsd = Jreg @ shapedirs    (24,3,10)
// ---------------------------------------------------------------------------
__global__ __launch_bounds__(256) void k_jreg(
    const float* __restrict__ Jreg,      // (24, V)
    const float* __restrict__ vtemp,     // (V, 3)
    const float* __restrict__ sdirs,     // (V, 3, 10)
    float* __restrict__ Jsd,             // (24, 3, 10) ws
    float* __restrict__ Jt)              // (24, 3) ws
{
    int j = blockIdx.x;
    int tid = threadIdx.x;
    float acc[33];
#pragma unroll
    for (int i = 0; i < 33; ++i) acc[i] = 0.f;

    for (int v = tid; v < VV; v += 256) {
        float w = Jreg[j * VV + v];
#pragma unroll
        for (int c = 0; c < 3; ++c) {
            acc[30 + c] += w * vtemp[v * 3 + c];
#pragma unroll
            for (int l = 0; l < NBETA; ++l)
                acc[c * NBETA + l] += w * sdirs[(v * 3 + c) * NBETA + l];
        }
    }

#pragma unroll
    for (int i = 0; i < 33; ++i) {
        float x = acc[i];
        for (int off = 32; off > 0; off >>= 1) x += __shfl_down(x, off);
        acc[i] = x;
    }
    __shared__ float sred[33][4];
    int wave = tid >> 6, lane = tid & 63;
    if (lane == 0) {
#pragma unroll
        for (int i = 0; i < 33; ++i) sred[i][wave] = acc[i];
    }
    __syncthreads();
    if (tid == 0) {
#pragma unroll
        for (int i = 0; i < 33; ++i) {
            float s = sred[i][0] + sred[i][1] + sred[i][2] + sred[i][3];
            if (i < 30) Jsd[j * 30 + i] = s;
            else        Jt[j * 3 + (i - 30)] = s;
        }
    }
}

// ---------------------------------------------------------------------------
// Kernel 2: per-batch — rodrigues, kinematic chain, rel transforms,
// pose_feature, posed joints (+transl).
// ---------------------------------------------------------------------------
__global__ __launch_bounds__(32) void k_batch(
    const float* __restrict__ transl,    // (B,3)
    const float* __restrict__ orient,    // (B,3)
    const float* __restrict__ betas,     // (B,10)
    const float* __restrict__ bpose,     // (B,69)
    const float* __restrict__ Jsd,       // (24,3,10)
    const float* __restrict__ Jt,        // (24,3)
    float* __restrict__ pfeat,           // (B,207) ws
    float* __restrict__ relt,            // (B,24,12) ws
    float* __restrict__ joints_out)      // (B,24,3)
{
    int t = threadIdx.x;
    int b = blockIdx.x * 32 + t;

    __shared__ float chain[NJ][12][32];

    float bet[NBETA];
#pragma unroll
    for (int l = 0; l < NBETA; ++l) bet[l] = betas[b * NBETA + l];

    float jx[NJ], jy[NJ], jz[NJ];
#pragma unroll
    for (int j = 0; j < NJ; ++j) {
        float a = Jt[j * 3 + 0], bb = Jt[j * 3 + 1], cc = Jt[j * 3 + 2];
#pragma unroll
        for (int l = 0; l < NBETA; ++l) {
            a  += Jsd[j * 30 + 0 * NBETA + l] * bet[l];
            bb += Jsd[j * 30 + 1 * NBETA + l] * bet[l];
            cc += Jsd[j * 30 + 2 * NBETA + l] * bet[l];
        }
        jx[j] = a; jy[j] = bb; jz[j] = cc;
    }

    float tr0 = transl[b * 3 + 0], tr1 = transl[b * 3 + 1], tr2 = transl[b * 3 + 2];

    for (int j = 0; j < NJ; ++j) {
        float rx, ry, rz;
        if (j == 0) {
            rx = orient[b * 3 + 0]; ry = orient[b * 3 + 1]; rz = orient[b * 3 + 2];
        } else {
            rx = bpose[b * 69 + (j - 1) * 3 + 0];
            ry = bpose[b * 69 + (j - 1) * 3 + 1];
            rz = bpose[b * 69 + (j - 1) * 3 + 2];
        }
        float ax = rx + 1e-8f, ay = ry + 1e-8f, az = rz + 1e-8f;
        float angle = sqrtf(ax * ax + ay * ay + az * az);
        float inv = 1.f / angle;
        float kx = rx * inv, ky = ry * inv, kz = rz * inv;
        float s = sinf(angle), c = cosf(angle), omc = 1.f - c;
        float R[9];
        R[0] = 1.f - omc * (ky * ky + kz * kz);
        R[1] = -s * kz + omc * (kx * ky);
        R[2] =  s * ky + omc * (kx * kz);
        R[3] =  s * kz + omc * (kx * ky);
        R[4] = 1.f - omc * (kx * kx + kz * kz);
        R[5] = -s * kx + omc * (ky * kz);
        R[6] = -s * ky + omc * (kx * kz);
        R[7] =  s * kx + omc * (ky * kz);
        R[8] = 1.f - omc * (kx * kx + ky * ky);

        if (j > 0) {
#pragma unroll
            for (int e = 0; e < 9; ++e) {
                float val = R[e] - ((e == 0 || e == 4 || e == 8) ? 1.f : 0.f);
                pfeat[b * PF + (j - 1) * 9 + e] = val;
            }
        }

        int p = kParents[j];
        float tx, ty, tz;
        if (j == 0) { tx = jx[0]; ty = jy[0]; tz = jz[0]; }
        else        { tx = jx[j] - jx[p]; ty = jy[j] - jy[p]; tz = jz[j] - jz[p]; }

        float A[12];
        if (j == 0) {
            A[0] = R[0]; A[1] = R[1]; A[2]  = R[2]; A[3]  = tx;
            A[4] = R[3]; A[5] = R[4]; A[6]  = R[5]; A[7]  = ty;
            A[8] = R[6]; A[9] = R[7]; A[10] = R[8]; A[11] = tz;
        } else {
            float P[12];
#pragma unroll
            for (int e = 0; e < 12; ++e) P[e] = chain[p][e][t];
#pragma unroll
            for (int r = 0; r < 3; ++r) {
#pragma unroll
                for (int cc = 0; cc < 3; ++cc)
                    A[r * 4 + cc] = P[r * 4 + 0] * R[0 * 3 + cc] +
                                    P[r * 4 + 1] * R[1 * 3 + cc] +
                                    P[r * 4 + 2] * R[2 * 3 + cc];
                A[r * 4 + 3] = P[r * 4 + 0] * tx + P[r * 4 + 1] * ty +
                               P[r * 4 + 2] * tz + P[r * 4 + 3];
            }
        }
#pragma unroll
        for (int e = 0; e < 12; ++e) chain[j][e][t] = A[e];

        joints_out[(b * NJ + j) * 3 + 0] = A[3]  + tr0;
        joints_out[(b * NJ + j) * 3 + 1] = A[7]  + tr1;
        joints_out[(b * NJ + j) * 3 + 2] = A[11] + tr2;

        float bx = A[0] * jx[j] + A[1] * jy[j] + A[2]  * jz[j];
        float by = A[4] * jx[j] + A[5] * jy[j] + A[6]  * jz[j];
        float bz = A[8] * jx[j] + A[9] * jy[j] + A[10] * jz[j];
        float* rt = relt + (b * NJ + j) * 12;
        rt[0] = A[0]; rt[1] = A[1]; rt[2]  = A[2];  rt[3]  = A[3]  - bx;
        rt[4] = A[4]; rt[5] = A[5]; rt[6]  = A[6];  rt[7]  = A[7]  - by;
        rt[8] = A[8]; rt[9] = A[9]; rt[10] = A[10]; rt[11] = A[11] - bz;
    }
}

// ---------------------------------------------------------------------------
// Kernel 3: fused vertex kernel, batch-tiled.
// Block = TB=16 batches × 256 vertices. grid = (B/TB, ceil(V/256)).
// gridDim.x = batch-tiles so consecutive block IDs share the same posedirs
// v-slice (636 KB << 4 MB per-XCD L2).
// ---------------------------------------------------------------------------
__global__ __launch_bounds__(256) void k_verts(
    const float* __restrict__ vtemp,     // (V,3)
    const float* __restrict__ sdirs,     // (V,3,10)
    const float* __restrict__ pdirs,     // (207, V*3)
    const float* __restrict__ lbsw,      // (V,24)
    const float* __restrict__ betas,     // (B,10)
    const float* __restrict__ transl,    // (B,3)
    const float* __restrict__ pfeat,     // (B,207)
    const float* __restrict__ relt,      // (B,24,12)
    float* __restrict__ verts)           // (B,V,3)
{
    int bt = blockIdx.x;            // batch tile [0,64)
    int vt = blockIdx.y;            // vertex tile [0,27)
    int t  = threadIdx.x;
    int v  = vt * 256 + t;
    int b0 = bt * TB;

    __shared__ float s_pf[PF][TB];       // transposed: [k][b] -> float4-readable
    __shared__ float s_rel[TB][NJ * 12];
    __shared__ float s_bet[TB][NBETA];
    __shared__ float s_tr[TB][3];

    for (int i = t; i < TB * PF; i += 256) {
        int b = i / PF, k = i % PF;
        s_pf[k][b] = pfeat[(size_t)(b0 + b) * PF + k];
    }
    for (int i = t; i < TB * NJ * 12; i += 256)
        s_rel[i / (NJ * 12)][i % (NJ * 12)] = relt[(size_t)b0 * NJ * 12 + i];
    if (t < TB * NBETA) s_bet[t / NBETA][t % NBETA] = betas[(size_t)b0 * NBETA + t];
    if (t >= 64 && t < 64 + TB * 3) {
        int i = t - 64;
        s_tr[i / 3][i % 3] = transl[(size_t)b0 * 3 + i];
    }
    __syncthreads();

    if (v >= VV) return;

    // accumulators: v_posed per batch
    float a0[TB], a1[TB], a2[TB];
    float vt0 = vtemp[v * 3 + 0], vt1 = vtemp[v * 3 + 1], vt2 = vtemp[v * 3 + 2];
#pragma unroll
    for (int b = 0; b < TB; ++b) { a0[b] = vt0; a1[b] = vt1; a2[b] = vt2; }

    // v_shaped: += sdirs[v,c,l] * beta[b,l]
#pragma unroll
    for (int l = 0; l < NBETA; ++l) {
        float s0 = sdirs[(v * 3 + 0) * NBETA + l];
        float s1 = sdirs[(v * 3 + 1) * NBETA + l];
        float s2 = sdirs[(v * 3 + 2) * NBETA + l];
#pragma unroll
        for (int b = 0; b < TB; ++b) {
            float be = s_bet[b][l];
            a0[b] += s0 * be; a1[b] += s1 * be; a2[b] += s2 * be;
        }
    }

    // pose offsets: += pf[b,k] * posedirs[k, v*3+c]
    const float* pd = pdirs + (size_t)v * 3;
    for (int k = 0; k < PF; ++k) {
        float d0 = pd[(size_t)k * V3 + 0];
        float d1 = pd[(size_t)k * V3 + 1];
        float d2 = pd[(size_t)k * V3 + 2];
        const float4* pfrow = (const float4*)&s_pf[k][0];
        float fbv[TB];
        *(float4*)&fbv[0]  = pfrow[0];
        *(float4*)&fbv[4]  = pfrow[1];
        *(float4*)&fbv[8]  = pfrow[2];
        *(float4*)&fbv[12] = pfrow[3];
#pragma unroll
        for (int b = 0; b < TB; ++b) {
            a0[b] += fbv[b] * d0;
            a1[b] += fbv[b] * d1;
            a2[b] += fbv[b] * d2;
        }
    }

    // LBS weights for this vertex
    float w[NJ];
#pragma unroll
    for (int j = 0; j < NJ; j += 4)
        *(float4*)&w[j] = *(const float4*)&lbsw[(size_t)v * NJ + j];

#pragma unroll
    for (int b = 0; b < TB; ++b) {
        float T[12];
#pragma unroll
        for (int e = 0; e < 12; ++e) T[e] = 0.f;
#pragma unroll
        for (int j = 0; j < NJ; ++j) {
            float wj = w[j];
            const float4* rr = (const float4*)&s_rel[b][j * 12];
            float4 r0 = rr[0], r1 = rr[1], r2 = rr[2];
            T[0] += wj * r0.x; T[1] += wj * r0.y; T[2]  += wj * r0.z; T[3]  += wj * r0.w;
            T[4] += wj * r1.x; T[5] += wj * r1.y; T[6]  += wj * r1.z; T[7]  += wj * r1.w;
            T[8] += wj * r2.x; T[9] += wj * r2.y; T[10] += wj * r2.z; T[11] += wj * r2.w;
        }
        float vp0 = a0[b], vp1 = a1[b], vp2 = a2[b];
        float o0 = T[0] * vp0 + T[1] * vp1 + T[2]  * vp2 + T[3]  + s_tr[b][0];
        float o1 = T[4] * vp0 + T[5] * vp1 + T[6]  * vp2 + T[7]  + s_tr[b][1];
        float o2 = T[8] * vp0 + T[9] * vp1 + T[10] * vp2 + T[11] + s_tr[b][2];
        float* o = verts + ((size_t)(b0 + b) * VV + v) * 3;
        o[0] = o0; o[1] = o1; o[2] = o2;
    }
}

extern "C" void kernel_launch(void* const* d_in, const int* in_sizes, int n_in,
                              void* d_out, int out_size, void* d_ws, size_t ws_size,
                              hipStream_t stream) {
    const float* transl = (const float*)d_in[0];
    const float* orient = (const float*)d_in[1];
    const float* betas  = (const float*)d_in[2];
    const float* bpose  = (const float*)d_in[3];
    const float* vtemp  = (const float*)d_in[4];
    const float* sdirs  = (const float*)d_in[5];
    const float* pdirs  = (const float*)d_in[6];
    const float* jreg   = (const float*)d_in[7];
    const float* lbsw   = (const float*)d_in[8];

    float* out = (float*)d_out;
    float* verts_out  = out;
    float* joints_out = out + (size_t)BB * VV * 3;

    float* ws    = (float*)d_ws;
    float* Jsd   = ws;                         // 720
    float* Jt    = ws + 720;                   // 72
    float* pfeat = ws + 792;                   // B*207
    float* relt  = ws + 792 + (size_t)BB * PF; // B*288

    k_jreg<<<NJ, 256, 0, stream>>>(jreg, vtemp, sdirs, Jsd, Jt);
    k_batch<<<BB / 32, 32, 0, stream>>>(transl, orient, betas, bpose,
                                        Jsd, Jt, pfeat, relt, joints_out);
    dim3 g(BB / TB, (VV + 255) / 256);
    k_verts<<<g, 256, 0, stream>>>(vtemp, sdirs, pdirs, lbsw, betas, transl,
                                   pfeat, relt, verts_out);
}

// Round 3
// 297.744 us; speedup vs baseline: 7.6447x; 1.1364x over previous
//
#include <hip/hip_runtime.h>

#define BB 1024
#define VV 6890
#define NJ 24
#define NBETA 10
#define PF 207          // (J-1)*9
#define V3 (VV*3)       // 20670
#define TB 16           // batches per block in k_verts

__device__ __constant__ int kParents[NJ] = {-1,0,0,0,1,2,3,4,5,6,7,8,9,9,9,12,13,14,16,17,18,19,20,21};

// ---------------------------------------------------------------------------
// Kernel 1: precompute Jt = Jreg @ v_template  (24,3)
//           and      Jsd = Jreg @ shapedirs    (24,3,10)
// ---------------------------------------------------------------------------
__global__ __launch_bounds__(256) void k_jreg(
    const float* __restrict__ Jreg,      // (24, V)
    const float* __restrict__ vtemp,     // (V, 3)
    const float* __restrict__ sdirs,     // (V, 3, 10)
    float* __restrict__ Jsd,             // (24, 3, 10) ws
    float* __restrict__ Jt)              // (24, 3) ws
{
    int j = blockIdx.x;
    int tid = threadIdx.x;
    float acc[33];
#pragma unroll
    for (int i = 0; i < 33; ++i) acc[i] = 0.f;

    for (int v = tid; v < VV; v += 256) {
        float w = Jreg[j * VV + v];
#pragma unroll
        for (int c = 0; c < 3; ++c) {
            acc[30 + c] += w * vtemp[v * 3 + c];
#pragma unroll
            for (int l = 0; l < NBETA; ++l)
                acc[c * NBETA + l] += w * sdirs[(v * 3 + c) * NBETA + l];
        }
    }

#pragma unroll
    for (int i = 0; i < 33; ++i) {
        float x = acc[i];
        for (int off = 32; off > 0; off >>= 1) x += __shfl_down(x, off);
        acc[i] = x;
    }
    __shared__ float sred[33][4];
    int wave = tid >> 6, lane = tid & 63;
    if (lane == 0) {
#pragma unroll
        for (int i = 0; i < 33; ++i) sred[i][wave] = acc[i];
    }
    __syncthreads();
    if (tid == 0) {
#pragma unroll
        for (int i = 0; i < 33; ++i) {
            float s = sred[i][0] + sred[i][1] + sred[i][2] + sred[i][3];
            if (i < 30) Jsd[j * 30 + i] = s;
            else        Jt[j * 3 + (i - 30)] = s;
        }
    }
}

// ---------------------------------------------------------------------------
// Kernel 2: per-batch — rodrigues, kinematic chain, rel transforms,
// pose_feature (TRANSPOSED to [PF][B] for scalar loads), posed joints.
// ---------------------------------------------------------------------------
__global__ __launch_bounds__(32) void k_batch(
    const float* __restrict__ transl,    // (B,3)
    const float* __restrict__ orient,    // (B,3)
    const float* __restrict__ betas,     // (B,10)
    const float* __restrict__ bpose,     // (B,69)
    const float* __restrict__ Jsd,       // (24,3,10)
    const float* __restrict__ Jt,        // (24,3)
    float* __restrict__ pfeatT,          // (PF, B) ws — transposed!
    float* __restrict__ relt,            // (B,24,12) ws
    float* __restrict__ joints_out)      // (B,24,3)
{
    int t = threadIdx.x;
    int b = blockIdx.x * 32 + t;

    __shared__ float chain[NJ][12][32];

    float bet[NBETA];
#pragma unroll
    for (int l = 0; l < NBETA; ++l) bet[l] = betas[b * NBETA + l];

    float jx[NJ], jy[NJ], jz[NJ];
#pragma unroll
    for (int j = 0; j < NJ; ++j) {
        float a = Jt[j * 3 + 0], bb = Jt[j * 3 + 1], cc = Jt[j * 3 + 2];
#pragma unroll
        for (int l = 0; l < NBETA; ++l) {
            a  += Jsd[j * 30 + 0 * NBETA + l] * bet[l];
            bb += Jsd[j * 30 + 1 * NBETA + l] * bet[l];
            cc += Jsd[j * 30 + 2 * NBETA + l] * bet[l];
        }
        jx[j] = a; jy[j] = bb; jz[j] = cc;
    }

    float tr0 = transl[b * 3 + 0], tr1 = transl[b * 3 + 1], tr2 = transl[b * 3 + 2];

    for (int j = 0; j < NJ; ++j) {
        float rx, ry, rz;
        if (j == 0) {
            rx = orient[b * 3 + 0]; ry = orient[b * 3 + 1]; rz = orient[b * 3 + 2];
        } else {
            rx = bpose[b * 69 + (j - 1) * 3 + 0];
            ry = bpose[b * 69 + (j - 1) * 3 + 1];
            rz = bpose[b * 69 + (j - 1) * 3 + 2];
        }
        float ax = rx + 1e-8f, ay = ry + 1e-8f, az = rz + 1e-8f;
        float angle = sqrtf(ax * ax + ay * ay + az * az);
        float inv = 1.f / angle;
        float kx = rx * inv, ky = ry * inv, kz = rz * inv;
        float s = sinf(angle), c = cosf(angle), omc = 1.f - c;
        float R[9];
        R[0] = 1.f - omc * (ky * ky + kz * kz);
        R[1] = -s * kz + omc * (kx * ky);
        R[2] =  s * ky + omc * (kx * kz);
        R[3] =  s * kz + omc * (kx * ky);
        R[4] = 1.f - omc * (kx * kx + kz * kz);
        R[5] = -s * kx + omc * (ky * kz);
        R[6] = -s * ky + omc * (kx * kz);
        R[7] =  s * kx + omc * (ky * kz);
        R[8] = 1.f - omc * (kx * kx + ky * ky);

        if (j > 0) {
#pragma unroll
            for (int e = 0; e < 9; ++e) {
                float val = R[e] - ((e == 0 || e == 4 || e == 8) ? 1.f : 0.f);
                pfeatT[(size_t)((j - 1) * 9 + e) * BB + b] = val;
            }
        }

        int p = kParents[j];
        float tx, ty, tz;
        if (j == 0) { tx = jx[0]; ty = jy[0]; tz = jz[0]; }
        else        { tx = jx[j] - jx[p]; ty = jy[j] - jy[p]; tz = jz[j] - jz[p]; }

        float A[12];
        if (j == 0) {
            A[0] = R[0]; A[1] = R[1]; A[2]  = R[2]; A[3]  = tx;
            A[4] = R[3]; A[5] = R[4]; A[6]  = R[5]; A[7]  = ty;
            A[8] = R[6]; A[9] = R[7]; A[10] = R[8]; A[11] = tz;
        } else {
            float P[12];
#pragma unroll
            for (int e = 0; e < 12; ++e) P[e] = chain[p][e][t];
#pragma unroll
            for (int r = 0; r < 3; ++r) {
#pragma unroll
                for (int cc = 0; cc < 3; ++cc)
                    A[r * 4 + cc] = P[r * 4 + 0] * R[0 * 3 + cc] +
                                    P[r * 4 + 1] * R[1 * 3 + cc] +
                                    P[r * 4 + 2] * R[2 * 3 + cc];
                A[r * 4 + 3] = P[r * 4 + 0] * tx + P[r * 4 + 1] * ty +
                               P[r * 4 + 2] * tz + P[r * 4 + 3];
            }
        }
#pragma unroll
        for (int e = 0; e < 12; ++e) chain[j][e][t] = A[e];

        joints_out[(b * NJ + j) * 3 + 0] = A[3]  + tr0;
        joints_out[(b * NJ + j) * 3 + 1] = A[7]  + tr1;
        joints_out[(b * NJ + j) * 3 + 2] = A[11] + tr2;

        float bx = A[0] * jx[j] + A[1] * jy[j] + A[2]  * jz[j];
        float by = A[4] * jx[j] + A[5] * jy[j] + A[6]  * jz[j];
        float bz = A[8] * jx[j] + A[9] * jy[j] + A[10] * jz[j];
        float* rt = relt + (b * NJ + j) * 12;
        rt[0] = A[0]; rt[1] = A[1]; rt[2]  = A[2];  rt[3]  = A[3]  - bx;
        rt[4] = A[4]; rt[5] = A[5]; rt[6]  = A[6];  rt[7]  = A[7]  - by;
        rt[8] = A[8]; rt[9] = A[9]; rt[10] = A[10]; rt[11] = A[11] - bz;
    }
}

// ---------------------------------------------------------------------------
// Kernel 3: fused vertex kernel, batch-tiled, ZERO LDS.
// All per-batch operands are wave-uniform -> read with uniform addresses so
// the compiler scalarizes them into SGPRs (s_load + v_fmac v,s,v).
// ---------------------------------------------------------------------------
__global__ __launch_bounds__(256) void k_verts(
    const float* __restrict__ vtemp,     // (V,3)
    const float* __restrict__ sdirs,     // (V,3,10)
    const float* __restrict__ pdirs,     // (207, V*3)
    const float* __restrict__ lbsw,      // (V,24)
    const float* __restrict__ betas,     // (B,10)
    const float* __restrict__ transl,    // (B,3)
    const float* __restrict__ pfeatT,    // (PF,B)
    const float* __restrict__ relt,      // (B,24*12)
    float* __restrict__ verts)           // (B,V,3)
{
    int bt = blockIdx.x;            // batch tile [0,64)
    int vt = blockIdx.y;            // vertex tile [0,27)
    int t  = threadIdx.x;
    int v  = vt * 256 + t;
    int b0 = bt * TB;

    if (v >= VV) return;            // no barriers in this kernel

    // --- template + shape blend ---
    float sd[30];
#pragma unroll
    for (int i = 0; i < 30; i += 2) {
        float2 x = *(const float2*)&sdirs[(size_t)v * 30 + i];
        sd[i] = x.x; sd[i + 1] = x.y;
    }
    float vt0 = vtemp[v * 3 + 0], vt1 = vtemp[v * 3 + 1], vt2 = vtemp[v * 3 + 2];

    float a0[TB], a1[TB], a2[TB];
#pragma unroll
    for (int b = 0; b < TB; ++b) {
        float x0 = vt0, x1 = vt1, x2 = vt2;
#pragma unroll
        for (int l = 0; l < NBETA; ++l) {
            float be = betas[(size_t)(b0 + b) * NBETA + l];   // uniform -> SGPR
            x0 += sd[l] * be;
            x1 += sd[10 + l] * be;
            x2 += sd[20 + l] * be;
        }
        a0[b] = x0; a1[b] = x1; a2[b] = x2;
    }

    // --- pose offsets: a[b] += pfeatT[k][b0+b] * posedirs[k, v*3+c] ---
    const float* pd = pdirs + (size_t)v * 3;
#pragma unroll 3
    for (int k = 0; k < PF; ++k) {
        float d0 = pd[(size_t)k * V3 + 0];
        float d1 = pd[(size_t)k * V3 + 1];
        float d2 = pd[(size_t)k * V3 + 2];
        const float* pfk = pfeatT + (size_t)k * BB + b0;      // uniform -> s_load_dwordx16
#pragma unroll
        for (int b = 0; b < TB; ++b) {
            float f = pfk[b];
            a0[b] += f * d0;
            a1[b] += f * d1;
            a2[b] += f * d2;
        }
    }

    // --- LBS weights (per-thread) ---
    float w[NJ];
#pragma unroll
    for (int j = 0; j < NJ; j += 4)
        *(float4*)&w[j] = *(const float4*)&lbsw[(size_t)v * NJ + j];

    // --- per-batch: blend transforms (SGPR) + apply + store ---
    for (int b = 0; b < TB; ++b) {
        const float* rb = relt + (size_t)(b0 + b) * (NJ * 12);  // uniform -> s_load
        float T[12];
#pragma unroll
        for (int e = 0; e < 12; ++e) T[e] = 0.f;
#pragma unroll
        for (int j = 0; j < NJ; ++j) {
            float wj = w[j];
#pragma unroll
            for (int e = 0; e < 12; ++e)
                T[e] += wj * rb[j * 12 + e];
        }
        float tr0 = transl[(size_t)(b0 + b) * 3 + 0];           // uniform
        float tr1 = transl[(size_t)(b0 + b) * 3 + 1];
        float tr2 = transl[(size_t)(b0 + b) * 3 + 2];
        float vp0 = a0[b], vp1 = a1[b], vp2 = a2[b];
        float o0 = T[0] * vp0 + T[1] * vp1 + T[2]  * vp2 + T[3]  + tr0;
        float o1 = T[4] * vp0 + T[5] * vp1 + T[6]  * vp2 + T[7]  + tr1;
        float o2 = T[8] * vp0 + T[9] * vp1 + T[10] * vp2 + T[11] + tr2;
        float* o = verts + ((size_t)(b0 + b) * VV + v) * 3;
        o[0] = o0; o[1] = o1; o[2] = o2;
    }
}

extern "C" void kernel_launch(void* const* d_in, const int* in_sizes, int n_in,
                              void* d_out, int out_size, void* d_ws, size_t ws_size,
                              hipStream_t stream) {
    const float* transl = (const float*)d_in[0];
    const float* orient = (const float*)d_in[1];
    const float* betas  = (const float*)d_in[2];
    const float* bpose  = (const float*)d_in[3];
    const float* vtemp  = (const float*)d_in[4];
    const float* sdirs  = (const float*)d_in[5];
    const float* pdirs  = (const float*)d_in[6];
    const float* jreg   = (const float*)d_in[7];
    const float* lbsw   = (const float*)d_in[8];

    float* out = (float*)d_out;
    float* verts_out  = out;
    float* joints_out = out + (size_t)BB * VV * 3;

    float* ws     = (float*)d_ws;
    float* Jsd    = ws;                          // 720
    float* Jt     = ws + 720;                    // 72
    float* pfeatT = ws + 792;                    // PF*B
    float* relt   = ws + 792 + (size_t)PF * BB;  // B*288

    k_jreg<<<NJ, 256, 0, stream>>>(jreg, vtemp, sdirs, Jsd, Jt);
    k_batch<<<BB / 32, 32, 0, stream>>>(transl, orient, betas, bpose,
                                        Jsd, Jt, pfeatT, relt, joints_out);
    dim3 g(BB / TB, (VV + 255) / 256);
    k_verts<<<g, 256, 0, stream>>>(vtemp, sdirs, pdirs, lbsw, betas, transl,
                                   pfeatT, relt, verts_out);
}

// Round 4
// 238.190 us; speedup vs baseline: 9.5561x; 1.2500x over previous
//
#include <hip/hip_runtime.h>

#define BB 1024
#define VV 6890
#define NJ 24
#define NBETA 10
#define PF 207          // (J-1)*9
#define V3 (VV*3)       // 20670
#define KP 224          // K padded to 7*32
#define VTB 64          // vertices per block tile in k_main
#define M3 (VTB*3)      // 192 v3-rows per tile
#define NVT ((VV + VTB - 1) / VTB)   // 108
#define V3PAD (NVT * VTB * 3)        // 20736 rows in pdirsT

typedef float f32x4 __attribute__((ext_vector_type(4)));
typedef short s16x8 __attribute__((ext_vector_type(8)));

__device__ __constant__ int kParents[NJ] = {-1,0,0,0,1,2,3,4,5,6,7,8,9,9,9,12,13,14,16,17,18,19,20,21};

__device__ __forceinline__ unsigned short f2bf(float x) {
    unsigned int u = __float_as_uint(x);
    unsigned int r = (u + 0x7fffu + ((u >> 16) & 1u)) >> 16;
    return (unsigned short)r;
}

// ---------------------------------------------------------------------------
// Kernel 0: transpose+cast posedirs (207, V3) fp32 -> pdT (V3PAD, KP) bf16.
// Zero-padded in k (207..223) and in rows (>= 20670).
// ---------------------------------------------------------------------------
__global__ __launch_bounds__(256) void k_prep(
    const float* __restrict__ pdirs,
    unsigned short* __restrict__ pdT)
{
    int v3b = blockIdx.x * 64;
    int t = threadIdx.x;
    __shared__ float tile[32][65];
    int vo  = t & 63;
    int kk0 = t >> 6;               // 0..3

    for (int kc = 0; kc < KP; kc += 32) {
#pragma unroll
        for (int r = 0; r < 8; ++r) {
            int kk = kk0 + 4 * r;   // covers 0..31
            int k  = kc + kk;
            int v3 = v3b + vo;
            float val = (k < PF && v3 < V3) ? pdirs[(size_t)k * V3 + v3] : 0.f;
            tile[kk][vo] = val;
        }
        __syncthreads();
        int vo2 = t >> 2;           // 0..63
        int ko  = (t & 3) * 8;      // 0,8,16,24
        union { s16x8 v; unsigned short u[8]; } pk;
#pragma unroll
        for (int i = 0; i < 8; ++i)
            pk.u[i] = f2bf(tile[ko + i][vo2]);
        *(s16x8*)(pdT + (size_t)(v3b + vo2) * KP + kc + ko) = pk.v;
        __syncthreads();
    }
}

// ---------------------------------------------------------------------------
// Kernel 1: Jt = Jreg @ v_template (24,3); Jsd = Jreg @ shapedirs (24,3,10)
// ---------------------------------------------------------------------------
__global__ __launch_bounds__(256) void k_jreg(
    const float* __restrict__ Jreg,
    const float* __restrict__ vtemp,
    const float* __restrict__ sdirs,
    float* __restrict__ Jsd,
    float* __restrict__ Jt)
{
    int j = blockIdx.x;
    int tid = threadIdx.x;
    float acc[33];
#pragma unroll
    for (int i = 0; i < 33; ++i) acc[i] = 0.f;

    for (int v = tid; v < VV; v += 256) {
        float w = Jreg[j * VV + v];
#pragma unroll
        for (int c = 0; c < 3; ++c) {
            acc[30 + c] += w * vtemp[v * 3 + c];
#pragma unroll
            for (int l = 0; l < NBETA; ++l)
                acc[c * NBETA + l] += w * sdirs[(v * 3 + c) * NBETA + l];
        }
    }

#pragma unroll
    for (int i = 0; i < 33; ++i) {
        float x = acc[i];
        for (int off = 32; off > 0; off >>= 1) x += __shfl_down(x, off);
        acc[i] = x;
    }
    __shared__ float sred[33][4];
    int wave = tid >> 6, lane = tid & 63;
    if (lane == 0) {
#pragma unroll
        for (int i = 0; i < 33; ++i) sred[i][wave] = acc[i];
    }
    __syncthreads();
    if (tid == 0) {
#pragma unroll
        for (int i = 0; i < 33; ++i) {
            float s = sred[i][0] + sred[i][1] + sred[i][2] + sred[i][3];
            if (i < 30) Jsd[j * 30 + i] = s;
            else        Jt[j * 3 + (i - 30)] = s;
        }
    }
}

// ---------------------------------------------------------------------------
// Kernel 2: per-batch — rodrigues, kinematic chain, rel transforms,
// pose_feature as bf16 [b][KP] (zero-padded), posed joints.
// ---------------------------------------------------------------------------
__global__ __launch_bounds__(32) void k_batch(
    const float* __restrict__ transl,
    const float* __restrict__ orient,
    const float* __restrict__ betas,
    const float* __restrict__ bpose,
    const float* __restrict__ Jsd,
    const float* __restrict__ Jt,
    unsigned short* __restrict__ pfB,    // (B, KP) bf16
    float* __restrict__ relt,            // (B, 24*12)
    float* __restrict__ joints_out)      // (B, 24, 3)
{
    int t = threadIdx.x;
    int b = blockIdx.x * 32 + t;

    __shared__ float chain[NJ][12][32];

    float bet[NBETA];
#pragma unroll
    for (int l = 0; l < NBETA; ++l) bet[l] = betas[b * NBETA + l];

    float jx[NJ], jy[NJ], jz[NJ];
#pragma unroll
    for (int j = 0; j < NJ; ++j) {
        float a = Jt[j * 3 + 0], bb = Jt[j * 3 + 1], cc = Jt[j * 3 + 2];
#pragma unroll
        for (int l = 0; l < NBETA; ++l) {
            a  += Jsd[j * 30 + 0 * NBETA + l] * bet[l];
            bb += Jsd[j * 30 + 1 * NBETA + l] * bet[l];
            cc += Jsd[j * 30 + 2 * NBETA + l] * bet[l];
        }
        jx[j] = a; jy[j] = bb; jz[j] = cc;
    }

    float tr0 = transl[b * 3 + 0], tr1 = transl[b * 3 + 1], tr2 = transl[b * 3 + 2];

    for (int j = 0; j < NJ; ++j) {
        float rx, ry, rz;
        if (j == 0) {
            rx = orient[b * 3 + 0]; ry = orient[b * 3 + 1]; rz = orient[b * 3 + 2];
        } else {
            rx = bpose[b * 69 + (j - 1) * 3 + 0];
            ry = bpose[b * 69 + (j - 1) * 3 + 1];
            rz = bpose[b * 69 + (j - 1) * 3 + 2];
        }
        float ax = rx + 1e-8f, ay = ry + 1e-8f, az = rz + 1e-8f;
        float angle = sqrtf(ax * ax + ay * ay + az * az);
        float inv = 1.f / angle;
        float kx = rx * inv, ky = ry * inv, kz = rz * inv;
        float s = sinf(angle), c = cosf(angle), omc = 1.f - c;
        float R[9];
        R[0] = 1.f - omc * (ky * ky + kz * kz);
        R[1] = -s * kz + omc * (kx * ky);
        R[2] =  s * ky + omc * (kx * kz);
        R[3] =  s * kz + omc * (kx * ky);
        R[4] = 1.f - omc * (kx * kx + kz * kz);
        R[5] = -s * kx + omc * (ky * kz);
        R[6] = -s * ky + omc * (kx * kz);
        R[7] =  s * kx + omc * (ky * kz);
        R[8] = 1.f - omc * (kx * kx + ky * ky);

        if (j > 0) {
#pragma unroll
            for (int e = 0; e < 9; ++e) {
                float val = R[e] - ((e == 0 || e == 4 || e == 8) ? 1.f : 0.f);
                pfB[(size_t)b * KP + (j - 1) * 9 + e] = f2bf(val);
            }
        }

        int p = kParents[j];
        float tx, ty, tz;
        if (j == 0) { tx = jx[0]; ty = jy[0]; tz = jz[0]; }
        else        { tx = jx[j] - jx[p]; ty = jy[j] - jy[p]; tz = jz[j] - jz[p]; }

        float A[12];
        if (j == 0) {
            A[0] = R[0]; A[1] = R[1]; A[2]  = R[2]; A[3]  = tx;
            A[4] = R[3]; A[5] = R[4]; A[6]  = R[5]; A[7]  = ty;
            A[8] = R[6]; A[9] = R[7]; A[10] = R[8]; A[11] = tz;
        } else {
            float P[12];
#pragma unroll
            for (int e = 0; e < 12; ++e) P[e] = chain[p][e][t];
#pragma unroll
            for (int r = 0; r < 3; ++r) {
#pragma unroll
                for (int cc = 0; cc < 3; ++cc)
                    A[r * 4 + cc] = P[r * 4 + 0] * R[0 * 3 + cc] +
                                    P[r * 4 + 1] * R[1 * 3 + cc] +
                                    P[r * 4 + 2] * R[2 * 3 + cc];
                A[r * 4 + 3] = P[r * 4 + 0] * tx + P[r * 4 + 1] * ty +
                               P[r * 4 + 2] * tz + P[r * 4 + 3];
            }
        }
#pragma unroll
        for (int e = 0; e < 12; ++e) chain[j][e][t] = A[e];

        joints_out[(b * NJ + j) * 3 + 0] = A[3]  + tr0;
        joints_out[(b * NJ + j) * 3 + 1] = A[7]  + tr1;
        joints_out[(b * NJ + j) * 3 + 2] = A[11] + tr2;

        float bx = A[0] * jx[j] + A[1] * jy[j] + A[2]  * jz[j];
        float by = A[4] * jx[j] + A[5] * jy[j] + A[6]  * jz[j];
        float bz = A[8] * jx[j] + A[9] * jy[j] + A[10] * jz[j];
        float* rt = relt + (b * NJ + j) * 12;
        rt[0] = A[0]; rt[1] = A[1]; rt[2]  = A[2];  rt[3]  = A[3]  - bx;
        rt[4] = A[4]; rt[5] = A[5]; rt[6]  = A[6];  rt[7]  = A[7]  - by;
        rt[8] = A[8]; rt[9] = A[9]; rt[10] = A[10]; rt[11] = A[11] - bz;
    }

    // zero-pad k = 207..223
    for (int k = PF; k < KP; ++k) pfB[(size_t)b * KP + k] = 0;
}

// ---------------------------------------------------------------------------
// Kernel 3: fused main. Block = 64 verts x 16 batches, 256 thr (4 waves).
// Pose GEMM on MFMA (bf16, fp32 accum) -> LDS; epilogue (shape blend + LBS +
// affine) on VALU with SGPR-resident per-batch operands.
// ---------------------------------------------------------------------------
__global__ __launch_bounds__(256) void k_main(
    const unsigned short* __restrict__ pdT,   // (V3PAD, KP) bf16
    const unsigned short* __restrict__ pfB,   // (BB, KP)   bf16
    const float* __restrict__ vtemp,          // (V,3)
    const float* __restrict__ sdirs,          // (V,30)
    const float* __restrict__ lbsw,           // (V,24)
    const float* __restrict__ betas,          // (B,10)
    const float* __restrict__ transl,         // (B,3)
    const float* __restrict__ relt,           // (B,288)
    float* __restrict__ verts)                // (B,V,3)
{
    int bt = blockIdx.x;            // batch tile 0..63
    int vt = blockIdx.y;            // vert tile 0..107
    int t  = threadIdx.x;
    int lane = t & 63;
    int w    = t >> 6;              // wave 0..3
    int b0   = bt * 16;
    int v3base = vt * M3;

    __shared__ float pose[M3 * 17];  // padded stride 17

    // ---- MFMA pose GEMM: C[v3][b] = sum_k pdT[v3][k] * pfB[b][k] ----
    int lr = lane & 15;              // A-row / B-col within tile
    int lk = (lane >> 4) * 8;        // k sub-offset
    f32x4 acc0 = {0.f,0.f,0.f,0.f};
    f32x4 acc1 = {0.f,0.f,0.f,0.f};
    f32x4 acc2 = {0.f,0.f,0.f,0.f};
    const unsigned short* pa = pdT + (size_t)(v3base + w * 48 + lr) * KP + lk;
    const unsigned short* pb = pfB + (size_t)(b0 + lr) * KP + lk;
#pragma unroll
    for (int ks = 0; ks < KP / 32; ++ks) {
        s16x8 bf = *(const s16x8*)(pb + ks * 32);
        s16x8 a0 = *(const s16x8*)(pa + ks * 32);
        s16x8 a1 = *(const s16x8*)(pa + (size_t)16 * KP + ks * 32);
        s16x8 a2 = *(const s16x8*)(pa + (size_t)32 * KP + ks * 32);
        acc0 = __builtin_amdgcn_mfma_f32_16x16x32_bf16(a0, bf, acc0, 0, 0, 0);
        acc1 = __builtin_amdgcn_mfma_f32_16x16x32_bf16(a1, bf, acc1, 0, 0, 0);
        acc2 = __builtin_amdgcn_mfma_f32_16x16x32_bf16(a2, bf, acc2, 0, 0, 0);
    }
    // C/D layout: col = lane&15, row = (lane>>4)*4 + reg  [verified m89/m91]
    int rbase = w * 48 + (lane >> 4) * 4;
#pragma unroll
    for (int r = 0; r < 4; ++r) {
        pose[(rbase + r) * 17 + lr]      = acc0[r];
        pose[(rbase + 16 + r) * 17 + lr] = acc1[r];
        pose[(rbase + 32 + r) * 17 + lr] = acc2[r];
    }
    __syncthreads();

    // ---- epilogue ----
    int v = vt * VTB + lane;
    if (v < VV) {
        float vt0 = vtemp[v * 3 + 0];
        float vt1 = vtemp[v * 3 + 1];
        float vt2 = vtemp[v * 3 + 2];
        float sd[30];
#pragma unroll
        for (int i = 0; i < 30; i += 2) {
            float2 x = *(const float2*)&sdirs[(size_t)v * 30 + i];
            sd[i] = x.x; sd[i + 1] = x.y;
        }
        float lw[NJ];
#pragma unroll
        for (int j = 0; j < NJ; j += 4)
            *(float4*)&lw[j] = *(const float4*)&lbsw[(size_t)v * NJ + j];

#pragma unroll
        for (int q = 0; q < 4; ++q) {
            int brl = q * 4 + w;                       // 0..15, wave-uniform
            int bu = __builtin_amdgcn_readfirstlane(b0 + brl);

            float x0 = vt0, x1 = vt1, x2 = vt2;
#pragma unroll
            for (int l = 0; l < NBETA; ++l) {
                float be = betas[(size_t)bu * NBETA + l];   // SGPR
                x0 += sd[l] * be;
                x1 += sd[10 + l] * be;
                x2 += sd[20 + l] * be;
            }
            x0 += pose[(3 * lane + 0) * 17 + brl];
            x1 += pose[(3 * lane + 1) * 17 + brl];
            x2 += pose[(3 * lane + 2) * 17 + brl];

            const float* rb = relt + (size_t)bu * (NJ * 12);  // SGPR loads
            float T[12];
#pragma unroll
            for (int e = 0; e < 12; ++e) T[e] = 0.f;
#pragma unroll
            for (int j = 0; j < NJ; ++j) {
                float wj = lw[j];
#pragma unroll
                for (int e = 0; e < 12; ++e)
                    T[e] += wj * rb[j * 12 + e];
            }
            float o0 = T[0] * x0 + T[1] * x1 + T[2]  * x2 + T[3]  + transl[(size_t)bu * 3 + 0];
            float o1 = T[4] * x0 + T[5] * x1 + T[6]  * x2 + T[7]  + transl[(size_t)bu * 3 + 1];
            float o2 = T[8] * x0 + T[9] * x1 + T[10] * x2 + T[11] + transl[(size_t)bu * 3 + 2];
            float* o = verts + ((size_t)(b0 + brl) * VV + v) * 3;
            o[0] = o0; o[1] = o1; o[2] = o2;
        }
    }
}

extern "C" void kernel_launch(void* const* d_in, const int* in_sizes, int n_in,
                              void* d_out, int out_size, void* d_ws, size_t ws_size,
                              hipStream_t stream) {
    const float* transl = (const float*)d_in[0];
    const float* orient = (const float*)d_in[1];
    const float* betas  = (const float*)d_in[2];
    const float* bpose  = (const float*)d_in[3];
    const float* vtemp  = (const float*)d_in[4];
    const float* sdirs  = (const float*)d_in[5];
    const float* pdirs  = (const float*)d_in[6];
    const float* jreg   = (const float*)d_in[7];
    const float* lbsw   = (const float*)d_in[8];

    float* out = (float*)d_out;
    float* verts_out  = out;
    float* joints_out = out + (size_t)BB * VV * 3;

    float* ws   = (float*)d_ws;
    float* Jsd  = ws;                              // 720 floats
    float* Jt   = ws + 720;                        // 72
    float* relt = ws + 792;                        // B*288 floats
    unsigned short* pfB = (unsigned short*)(ws + 792 + (size_t)BB * 288);  // B*KP bf16
    unsigned short* pdT = pfB + (size_t)BB * KP;   // V3PAD*KP bf16 (~9.3 MB)

    k_prep<<<V3PAD / 64, 256, 0, stream>>>(pdirs, pdT);
    k_jreg<<<NJ, 256, 0, stream>>>(jreg, vtemp, sdirs, Jsd, Jt);
    k_batch<<<BB / 32, 32, 0, stream>>>(transl, orient, betas, bpose,
                                        Jsd, Jt, pfB, relt, joints_out);
    dim3 g(BB / 16, NVT);
    k_main<<<g, 256, 0, stream>>>(pdT, pfB, vtemp, sdirs, lbsw, betas, transl,
                                  relt, verts_out);
}

// Round 5
// 190.231 us; speedup vs baseline: 11.9653x; 1.2521x over previous
//
#include <hip/hip_runtime.h>

#define BB 1024
#define VV 6890
#define NJ 24
#define NBETA 10
#define PF 207            // (J-1)*9
#define V3 (VV*3)         // 20670
#define KP 224            // GEMM1 K: 207 pose + 10 shape + 2 vtemp(hi/lo) + 5 zero
#define VTB 64            // vertices per block tile in k_main
#define M3 (VTB*3)        // 192 v3-rows per tile
#define NVT ((VV + VTB - 1) / VTB)   // 108
#define V3PAD (NVT * VTB * 3)        // 20736 rows in pdT
#define VPAD (NVT * VTB)             // 6912 rows in lbswB
#define K2 96             // GEMM2 K: [w_hi|w_lo|w_hi] x [rel_hi|rel_hi|rel_lo]
#define NCH 8             // k_jreg chunks
#define CHV 862           // ceil(VV/NCH)

typedef float f32x4 __attribute__((ext_vector_type(4)));
typedef short s16x8 __attribute__((ext_vector_type(8)));

__device__ __constant__ int kParents[NJ] = {-1,0,0,0,1,2,3,4,5,6,7,8,9,9,9,12,13,14,16,17,18,19,20,21};

__device__ __forceinline__ unsigned short f2bf(float x) {
    unsigned int u = __float_as_uint(x);
    unsigned int r = (u + 0x7fffu + ((u >> 16) & 1u)) >> 16;
    return (unsigned short)r;
}
__device__ __forceinline__ float bf2f(unsigned short h) {
    return __uint_as_float((unsigned int)h << 16);
}

// ---------------------------------------------------------------------------
// k_prep: build GEMM1 A matrix, row v3 in [0, V3PAD), 224 bf16 cols:
//   [0..206]   = posedirs[k][v3]
//   [207..216] = sdirs[v3][l]          (shape dirs, transposed view)
//   [217]      = bf16_hi(vtemp[v3]); [218] = bf16(vtemp - hi)
//   [219..223] = 0;  rows >= V3 all zero
// ---------------------------------------------------------------------------
__global__ __launch_bounds__(256) void k_prep(
    const float* __restrict__ pdirs,     // (207, V3)
    const float* __restrict__ sdirs,     // (V3, 10) flat view of (V,3,10)
    const float* __restrict__ vtemp,     // (V3)
    unsigned short* __restrict__ pdT)    // (V3PAD, KP)
{
    int row = blockIdx.x * 256 + threadIdx.x;
    if (row >= V3PAD) return;
    bool valid = row < V3;
    unsigned short* o = pdT + (size_t)row * KP;
    for (int kc = 0; kc < KP; kc += 8) {
        union { s16x8 v; unsigned short u[8]; } pk;
#pragma unroll
        for (int i = 0; i < 8; ++i) {
            int k = kc + i;
            float val = 0.f;
            if (valid) {
                if (k < PF)                val = pdirs[(size_t)k * V3 + row];
                else if (k < PF + NBETA)   val = sdirs[(size_t)row * NBETA + (k - PF)];
                else if (k == PF + NBETA)  val = vtemp[row];
                else if (k == PF + NBETA + 1) {
                    float x = vtemp[row];
                    val = x - bf2f(f2bf(x));
                }
            }
            pk.u[i] = f2bf(val);
        }
        *(s16x8*)(o + kc) = pk.v;
    }
}

// ---------------------------------------------------------------------------
// k_lbsw: GEMM2 A matrix: row v, 96 bf16 cols = [w_hi(24) | w_lo(24) | w_hi(24) | 0]
// ---------------------------------------------------------------------------
__global__ __launch_bounds__(256) void k_lbsw(
    const float* __restrict__ lbsw,      // (V, 24)
    unsigned short* __restrict__ lbswB)  // (VPAD, 96)
{
    int v = blockIdx.x * 256 + threadIdx.x;
    if (v >= VPAD) return;
    bool valid = v < VV;
    unsigned short hi[NJ], lo[NJ];
#pragma unroll
    for (int j = 0; j < NJ; ++j) {
        float wv = valid ? lbsw[(size_t)v * NJ + j] : 0.f;
        hi[j] = f2bf(wv);
        lo[j] = f2bf(wv - bf2f(hi[j]));
    }
    unsigned short* o = lbswB + (size_t)v * K2;
    union { s16x8 v8; unsigned short u[8]; } pk;
#pragma unroll
    for (int c = 0; c < 3; ++c) {
#pragma unroll
        for (int g = 0; g < 3; ++g) {
#pragma unroll
            for (int i = 0; i < 8; ++i) {
                int j = g * 8 + i;
                pk.u[i] = (c == 1) ? lo[j] : hi[j];
            }
            *(s16x8*)(o + c * NJ + g * 8) = pk.v8;
        }
    }
#pragma unroll
    for (int i = 0; i < 8; ++i) pk.u[i] = 0;
    *(s16x8*)(o + 72) = pk.v8;
    *(s16x8*)(o + 80) = pk.v8;
    *(s16x8*)(o + 88) = pk.v8;
}

// ---------------------------------------------------------------------------
// k_jreg (chunked) + k_jred: Jt = Jreg @ v_template; Jsd = Jreg @ shapedirs
// ---------------------------------------------------------------------------
__global__ __launch_bounds__(256) void k_jreg(
    const float* __restrict__ Jreg,
    const float* __restrict__ vtemp,
    const float* __restrict__ sdirs,
    float* __restrict__ jpart)           // (24, NCH, 33)
{
    int j  = blockIdx.x;
    int ch = blockIdx.y;
    int tid = threadIdx.x;
    int v0 = ch * CHV;
    int vend = min(VV, v0 + CHV);

    float acc[33];
#pragma unroll
    for (int i = 0; i < 33; ++i) acc[i] = 0.f;

    for (int v = v0 + tid; v < vend; v += 256) {
        float w = Jreg[(size_t)j * VV + v];
#pragma unroll
        for (int c = 0; c < 3; ++c) {
            acc[30 + c] += w * vtemp[v * 3 + c];
#pragma unroll
            for (int l = 0; l < NBETA; ++l)
                acc[c * NBETA + l] += w * sdirs[(size_t)(v * 3 + c) * NBETA + l];
        }
    }

#pragma unroll
    for (int i = 0; i < 33; ++i) {
        float x = acc[i];
        for (int off = 32; off > 0; off >>= 1) x += __shfl_down(x, off);
        acc[i] = x;
    }
    __shared__ float sred[33][4];
    int wave = tid >> 6, lane = tid & 63;
    if (lane == 0) {
#pragma unroll
        for (int i = 0; i < 33; ++i) sred[i][wave] = acc[i];
    }
    __syncthreads();
    if (tid == 0) {
#pragma unroll
        for (int i = 0; i < 33; ++i)
            jpart[(size_t)(j * NCH + ch) * 33 + i] =
                sred[i][0] + sred[i][1] + sred[i][2] + sred[i][3];
    }
}

__global__ __launch_bounds__(256) void k_jred(
    const float* __restrict__ jpart,
    float* __restrict__ Jsd,             // (24,30)
    float* __restrict__ Jt)              // (24,3)
{
    for (int idx = threadIdx.x; idx < NJ * 33; idx += 256) {
        int j = idx / 33, i = idx % 33;
        float s = 0.f;
        for (int c = 0; c < NCH; ++c) s += jpart[(size_t)(j * NCH + c) * 33 + i];
        if (i < 30) Jsd[j * 30 + i] = s;
        else        Jt[j * 3 + (i - 30)] = s;
    }
}

// ---------------------------------------------------------------------------
// k_batch: rodrigues, kinematic chain, rel transforms (fp32 -> relt),
// pose features + betas + ones into pfB (bf16 B-matrix for GEMM1), joints.
// ---------------------------------------------------------------------------
__global__ __launch_bounds__(32) void k_batch(
    const float* __restrict__ transl,
    const float* __restrict__ orient,
    const float* __restrict__ betas,
    const float* __restrict__ bpose,
    const float* __restrict__ Jsd,
    const float* __restrict__ Jt,
    unsigned short* __restrict__ pfB,    // (B, KP) bf16
    float* __restrict__ relt,            // (B, 24*12)
    float* __restrict__ joints_out)      // (B, 24, 3)
{
    int t = threadIdx.x;
    int b = blockIdx.x * 32 + t;

    __shared__ float chain[NJ][12][32];

    float bet[NBETA];
#pragma unroll
    for (int l = 0; l < NBETA; ++l) bet[l] = betas[b * NBETA + l];

    float jx[NJ], jy[NJ], jz[NJ];
#pragma unroll
    for (int j = 0; j < NJ; ++j) {
        float a = Jt[j * 3 + 0], bb = Jt[j * 3 + 1], cc = Jt[j * 3 + 2];
#pragma unroll
        for (int l = 0; l < NBETA; ++l) {
            a  += Jsd[j * 30 + 0 * NBETA + l] * bet[l];
            bb += Jsd[j * 30 + 1 * NBETA + l] * bet[l];
            cc += Jsd[j * 30 + 2 * NBETA + l] * bet[l];
        }
        jx[j] = a; jy[j] = bb; jz[j] = cc;
    }

    float tr0 = transl[b * 3 + 0], tr1 = transl[b * 3 + 1], tr2 = transl[b * 3 + 2];

    for (int j = 0; j < NJ; ++j) {
        float rx, ry, rz;
        if (j == 0) {
            rx = orient[b * 3 + 0]; ry = orient[b * 3 + 1]; rz = orient[b * 3 + 2];
        } else {
            rx = bpose[b * 69 + (j - 1) * 3 + 0];
            ry = bpose[b * 69 + (j - 1) * 3 + 1];
            rz = bpose[b * 69 + (j - 1) * 3 + 2];
        }
        float ax = rx + 1e-8f, ay = ry + 1e-8f, az = rz + 1e-8f;
        float angle = sqrtf(ax * ax + ay * ay + az * az);
        float inv = 1.f / angle;
        float kx = rx * inv, ky = ry * inv, kz = rz * inv;
        float s = sinf(angle), c = cosf(angle), omc = 1.f - c;
        float R[9];
        R[0] = 1.f - omc * (ky * ky + kz * kz);
        R[1] = -s * kz + omc * (kx * ky);
        R[2] =  s * ky + omc * (kx * kz);
        R[3] =  s * kz + omc * (kx * ky);
        R[4] = 1.f - omc * (kx * kx + kz * kz);
        R[5] = -s * kx + omc * (ky * kz);
        R[6] = -s * ky + omc * (kx * kz);
        R[7] =  s * kx + omc * (ky * kz);
        R[8] = 1.f - omc * (kx * kx + ky * ky);

        if (j > 0) {
#pragma unroll
            for (int e = 0; e < 9; ++e) {
                float val = R[e] - ((e == 0 || e == 4 || e == 8) ? 1.f : 0.f);
                pfB[(size_t)b * KP + (j - 1) * 9 + e] = f2bf(val);
            }
        }

        int p = kParents[j];
        float tx, ty, tz;
        if (j == 0) { tx = jx[0]; ty = jy[0]; tz = jz[0]; }
        else        { tx = jx[j] - jx[p]; ty = jy[j] - jy[p]; tz = jz[j] - jz[p]; }

        float A[12];
        if (j == 0) {
            A[0] = R[0]; A[1] = R[1]; A[2]  = R[2]; A[3]  = tx;
            A[4] = R[3]; A[5] = R[4]; A[6]  = R[5]; A[7]  = ty;
            A[8] = R[6]; A[9] = R[7]; A[10] = R[8]; A[11] = tz;
        } else {
            float P[12];
#pragma unroll
            for (int e = 0; e < 12; ++e) P[e] = chain[p][e][t];
#pragma unroll
            for (int r = 0; r < 3; ++r) {
#pragma unroll
                for (int cc = 0; cc < 3; ++cc)
                    A[r * 4 + cc] = P[r * 4 + 0] * R[0 * 3 + cc] +
                                    P[r * 4 + 1] * R[1 * 3 + cc] +
                                    P[r * 4 + 2] * R[2 * 3 + cc];
                A[r * 4 + 3] = P[r * 4 + 0] * tx + P[r * 4 + 1] * ty +
                               P[r * 4 + 2] * tz + P[r * 4 + 3];
            }
        }
#pragma unroll
        for (int e = 0; e < 12; ++e) chain[j][e][t] = A[e];

        joints_out[(b * NJ + j) * 3 + 0] = A[3]  + tr0;
        joints_out[(b * NJ + j) * 3 + 1] = A[7]  + tr1;
        joints_out[(b * NJ + j) * 3 + 2] = A[11] + tr2;

        float bx = A[0] * jx[j] + A[1] * jy[j] + A[2]  * jz[j];
        float by = A[4] * jx[j] + A[5] * jy[j] + A[6]  * jz[j];
        float bz = A[8] * jx[j] + A[9] * jy[j] + A[10] * jz[j];
        float* rt = relt + (size_t)(b * NJ + j) * 12;
        rt[0] = A[0]; rt[1] = A[1]; rt[2]  = A[2];  rt[3]  = A[3]  - bx;
        rt[4] = A[4]; rt[5] = A[5]; rt[6]  = A[6];  rt[7]  = A[7]  - by;
        rt[8] = A[8]; rt[9] = A[9]; rt[10] = A[10]; rt[11] = A[11] - bz;
    }

    // pfB tail: betas, ones (for vtemp hi/lo), zero pad
#pragma unroll
    for (int l = 0; l < NBETA; ++l)
        pfB[(size_t)b * KP + PF + l] = f2bf(bet[l]);
    pfB[(size_t)b * KP + PF + NBETA]     = 0x3F80;  // 1.0
    pfB[(size_t)b * KP + PF + NBETA + 1] = 0x3F80;  // 1.0
    for (int k = PF + NBETA + 2; k < KP; ++k) pfB[(size_t)b * KP + k] = 0;
}

// ---------------------------------------------------------------------------
// k_relb: GEMM2 B matrix from relt: row (b*12+e), 96 bf16 cols =
//   [rel_hi(24) | rel_hi(24) | rel_lo(24) | 0(24)]
// ---------------------------------------------------------------------------
__global__ __launch_bounds__(256) void k_relb(
    const float* __restrict__ relt,      // (B, 24*12)
    unsigned short* __restrict__ relBT)  // (B*12, 96)
{
    int row = blockIdx.x * 256 + threadIdx.x;   // b*12 + e
    if (row >= BB * 12) return;
    int b = row / 12, e = row % 12;
    unsigned short hi[NJ], lo[NJ];
#pragma unroll
    for (int j = 0; j < NJ; ++j) {
        float val = relt[(size_t)b * 288 + j * 12 + e];
        hi[j] = f2bf(val);
        lo[j] = f2bf(val - bf2f(hi[j]));
    }
    unsigned short* o = relBT + (size_t)row * K2;
    union { s16x8 v8; unsigned short u[8]; } pk;
#pragma unroll
    for (int c = 0; c < 3; ++c) {
#pragma unroll
        for (int g = 0; g < 3; ++g) {
#pragma unroll
            for (int i = 0; i < 8; ++i) {
                int j = g * 8 + i;
                pk.u[i] = (c == 2) ? lo[j] : hi[j];
            }
            *(s16x8*)(o + c * NJ + g * 8) = pk.v8;
        }
    }
#pragma unroll
    for (int i = 0; i < 8; ++i) pk.u[i] = 0;
    *(s16x8*)(o + 72) = pk.v8;
    *(s16x8*)(o + 80) = pk.v8;
    *(s16x8*)(o + 88) = pk.v8;
}

// ---------------------------------------------------------------------------
// k_main: block = 64 verts x 16 batches, 256 thr (4 waves).
// GEMM1 (MFMA): x[v3][b] = v_posed (template+shape+pose fused in K)
// GEMM2 (MFMA): T[v][(b,e)] = LBS-blended transforms (hi/lo compensated)
// Epilogue: out = T * [x,1] + transl  (~30 VALU ops/thread/batch)
// ---------------------------------------------------------------------------
__global__ __launch_bounds__(256) void k_main(
    const unsigned short* __restrict__ pdT,    // (V3PAD, KP)
    const unsigned short* __restrict__ pfB,    // (BB, KP)
    const unsigned short* __restrict__ lbswB,  // (VPAD, 96)
    const unsigned short* __restrict__ relBT,  // (BB*12, 96)
    const float* __restrict__ transl,          // (B,3)
    float* __restrict__ verts)                 // (B,V,3)
{
    int bt = blockIdx.x;            // batch tile 0..63
    int vt = blockIdx.y;            // vert tile 0..107
    int t  = threadIdx.x;
    int lane = t & 63;
    int w    = t >> 6;
    int b0   = bt * 16;
    int v3base = vt * M3;

    __shared__ float xls[M3 * 17];      // x tile [v3local][b], stride 17
    __shared__ float Tls[192 * 65];     // T tile [be][v], stride 65

    int lr = lane & 15;
    int lk = (lane >> 4) * 8;

    // ---- GEMM1 ----
    {
        f32x4 acc0 = {0.f,0.f,0.f,0.f};
        f32x4 acc1 = {0.f,0.f,0.f,0.f};
        f32x4 acc2 = {0.f,0.f,0.f,0.f};
        const unsigned short* pa = pdT + (size_t)(v3base + w * 48 + lr) * KP + lk;
        const unsigned short* pb = pfB + (size_t)(b0 + lr) * KP + lk;
#pragma unroll
        for (int ks = 0; ks < KP / 32; ++ks) {
            s16x8 bf = *(const s16x8*)(pb + ks * 32);
            s16x8 a0 = *(const s16x8*)(pa + ks * 32);
            s16x8 a1 = *(const s16x8*)(pa + (size_t)16 * KP + ks * 32);
            s16x8 a2 = *(const s16x8*)(pa + (size_t)32 * KP + ks * 32);
            acc0 = __builtin_amdgcn_mfma_f32_16x16x32_bf16(a0, bf, acc0, 0, 0, 0);
            acc1 = __builtin_amdgcn_mfma_f32_16x16x32_bf16(a1, bf, acc1, 0, 0, 0);
            acc2 = __builtin_amdgcn_mfma_f32_16x16x32_bf16(a2, bf, acc2, 0, 0, 0);
        }
        int rbase = w * 48 + (lane >> 4) * 4;
#pragma unroll
        for (int r = 0; r < 4; ++r) {
            xls[(rbase + r) * 17 + lr]      = acc0[r];
            xls[(rbase + 16 + r) * 17 + lr] = acc1[r];
            xls[(rbase + 32 + r) * 17 + lr] = acc2[r];
        }
    }

    // ---- GEMM2: wave w handles N-tiles {3w..3w+2}, all 4 M-tiles ----
    {
        s16x8 af[4][3];
        const unsigned short* la = lbswB + (size_t)(vt * VTB + lr) * K2 + lk;
#pragma unroll
        for (int m = 0; m < 4; ++m)
#pragma unroll
            for (int ks = 0; ks < 3; ++ks)
                af[m][ks] = *(const s16x8*)(la + (size_t)m * 16 * K2 + ks * 32);

#pragma unroll
        for (int i = 0; i < 3; ++i) {
            int nt = w * 3 + i;
            const unsigned short* lb = relBT + (size_t)(b0 * 12 + nt * 16 + lr) * K2 + lk;
            s16x8 bf0 = *(const s16x8*)(lb);
            s16x8 bf1 = *(const s16x8*)(lb + 32);
            s16x8 bf2 = *(const s16x8*)(lb + 64);
#pragma unroll
            for (int m = 0; m < 4; ++m) {
                f32x4 acc = {0.f,0.f,0.f,0.f};
                acc = __builtin_amdgcn_mfma_f32_16x16x32_bf16(af[m][0], bf0, acc, 0, 0, 0);
                acc = __builtin_amdgcn_mfma_f32_16x16x32_bf16(af[m][1], bf1, acc, 0, 0, 0);
                acc = __builtin_amdgcn_mfma_f32_16x16x32_bf16(af[m][2], bf2, acc, 0, 0, 0);
                int be = nt * 16 + lr;
                int vb = m * 16 + (lane >> 4) * 4;
#pragma unroll
                for (int r = 0; r < 4; ++r)
                    Tls[be * 65 + vb + r] = acc[r];
            }
        }
    }

    __syncthreads();

    // ---- epilogue ----
    int v = vt * VTB + lane;
    if (v < VV) {
#pragma unroll
        for (int q = 0; q < 4; ++q) {
            int brl = q * 4 + w;                   // 0..15, wave-uniform
            int bu  = __builtin_amdgcn_readfirstlane(b0 + brl);

            float x0 = xls[(3 * lane + 0) * 17 + brl];
            float x1 = xls[(3 * lane + 1) * 17 + brl];
            float x2 = xls[(3 * lane + 2) * 17 + brl];

            float T[12];
#pragma unroll
            for (int e = 0; e < 12; ++e)
                T[e] = Tls[(brl * 12 + e) * 65 + lane];

            float o0 = T[0] * x0 + T[1] * x1 + T[2]  * x2 + T[3]  + transl[(size_t)bu * 3 + 0];
            float o1 = T[4] * x0 + T[5] * x1 + T[6]  * x2 + T[7]  + transl[(size_t)bu * 3 + 1];
            float o2 = T[8] * x0 + T[9] * x1 + T[10] * x2 + T[11] + transl[(size_t)bu * 3 + 2];

            float* o = verts + ((size_t)(b0 + brl) * VV + v) * 3;
            o[0] = o0; o[1] = o1; o[2] = o2;
        }
    }
}

extern "C" void kernel_launch(void* const* d_in, const int* in_sizes, int n_in,
                              void* d_out, int out_size, void* d_ws, size_t ws_size,
                              hipStream_t stream) {
    const float* transl = (const float*)d_in[0];
    const float* orient = (const float*)d_in[1];
    const float* betas  = (const float*)d_in[2];
    const float* bpose  = (const float*)d_in[3];
    const float* vtemp  = (const float*)d_in[4];
    const float* sdirs  = (const float*)d_in[5];
    const float* pdirs  = (const float*)d_in[6];
    const float* jreg   = (const float*)d_in[7];
    const float* lbsw   = (const float*)d_in[8];

    float* out = (float*)d_out;
    float* verts_out  = out;
    float* joints_out = out + (size_t)BB * VV * 3;

    float* ws    = (float*)d_ws;
    float* Jsd   = ws;                               // 720 f
    float* Jt    = ws + 720;                         // 72 f
    float* jpart = ws + 792;                         // 24*8*33 = 6336 f
    float* relt  = ws + 792 + 6336;                  // B*288 f
    size_t foff  = 792 + 6336 + (size_t)BB * 288;    // total floats = 302040
    unsigned short* pfB   = (unsigned short*)(ws + foff);          // B*KP
    unsigned short* pdT   = pfB + (size_t)BB * KP;                 // V3PAD*KP
    unsigned short* lbswB = pdT + (size_t)V3PAD * KP;              // VPAD*96
    unsigned short* relBT = lbswB + (size_t)VPAD * K2;             // B*12*96

    k_prep<<<V3PAD / 256, 256, 0, stream>>>(pdirs, sdirs, vtemp, pdT);
    k_lbsw<<<VPAD / 256, 256, 0, stream>>>(lbsw, lbswB);
    dim3 gj(NJ, NCH);
    k_jreg<<<gj, 256, 0, stream>>>(jreg, vtemp, sdirs, jpart);
    k_jred<<<1, 256, 0, stream>>>(jpart, Jsd, Jt);
    k_batch<<<BB / 32, 32, 0, stream>>>(transl, orient, betas, bpose,
                                        Jsd, Jt, pfB, relt, joints_out);
    k_relb<<<(BB * 12 + 255) / 256, 256, 0, stream>>>(relt, relBT);
    dim3 g(BB / 16, NVT);
    k_main<<<g, 256, 0, stream>>>(pdT, pfB, lbswB, relBT, transl, verts_out);
}

// Round 6
// 133.073 us; speedup vs baseline: 17.1047x; 1.4295x over previous
//
#include <hip/hip_runtime.h>

#define BB 1024
#define VV 6890
#define NJ 24
#define NBETA 10
#define PF 207            // (J-1)*9
#define V3 (VV*3)         // 20670
#define KP 224            // GEMM1 K: 207 pose + 10 shape + 2 vtemp(hi/lo) + 5 zero
#define VTB 64            // vertices per block tile in k_main
#define M3 (VTB*3)        // 192 v3-rows per tile
#define NVT ((VV + VTB - 1) / VTB)   // 108
#define V3PAD (NVT * VTB * 3)        // 20736 rows in pdT
#define VPAD (NVT * VTB)             // 6912 rows in lbswB
#define K2 32             // GEMM2 K: w_hi(24) x rel_hi(24), zero-padded
#define NCH 8             // jreg chunks
#define CHV 862           // ceil(VV/NCH)
#define NBLK_A (V3PAD / 256)         // 81
#define NBLK_B (VPAD / 256)          // 27
#define NBLK_C (NJ * NCH)            // 192
#define XS 19             // xls stride (floats)
#define TS 68             // Tls stride (bf16)

typedef float f32x4 __attribute__((ext_vector_type(4)));
typedef short s16x8 __attribute__((ext_vector_type(8)));
typedef short s16x4 __attribute__((ext_vector_type(4)));

__device__ __constant__ int kParents[NJ] = {-1,0,0,0,1,2,3,4,5,6,7,8,9,9,9,12,13,14,16,17,18,19,20,21};

__device__ __forceinline__ unsigned short f2bf(float x) {
    unsigned int u = __float_as_uint(x);
    unsigned int r = (u + 0x7fffu + ((u >> 16) & 1u)) >> 16;
    return (unsigned short)r;
}
__device__ __forceinline__ float bf2f(unsigned short h) {
    return __uint_as_float((unsigned int)h << 16);
}

// ---------------------------------------------------------------------------
// k_prep_all: 3 block-ranges:
//  A [0,81):    pdT rows — GEMM1 A matrix (posedirs | sdirs | vtemp hi/lo | 0)
//  B [81,108):  lbswB rows — GEMM2 A matrix (w_hi(24) | 0(8))
//  C [108,300): jreg partials (24 joints x 8 chunks)
// ---------------------------------------------------------------------------
__global__ __launch_bounds__(256) void k_prep_all(
    const float* __restrict__ pdirs,     // (207, V3)
    const float* __restrict__ sdirs,     // (V3, 10)
    const float* __restrict__ vtemp,     // (V3)
    const float* __restrict__ lbsw,      // (V, 24)
    const float* __restrict__ Jreg,      // (24, V)
    unsigned short* __restrict__ pdT,    // (V3PAD, KP)
    unsigned short* __restrict__ lbswB,  // (VPAD, K2)
    float* __restrict__ jpart)           // (24, NCH, 33)
{
    int bid = blockIdx.x;
    int t = threadIdx.x;

    if (bid < NBLK_A) {
        int row = bid * 256 + t;
        bool valid = row < V3;
        unsigned short* o = pdT + (size_t)row * KP;
        for (int kc = 0; kc < KP; kc += 8) {
            union { s16x8 v; unsigned short u[8]; } pk;
#pragma unroll
            for (int i = 0; i < 8; ++i) {
                int k = kc + i;
                float val = 0.f;
                if (valid) {
                    if (k < PF)                val = pdirs[(size_t)k * V3 + row];
                    else if (k < PF + NBETA)   val = sdirs[(size_t)row * NBETA + (k - PF)];
                    else if (k == PF + NBETA)  val = vtemp[row];
                    else if (k == PF + NBETA + 1) {
                        float x = vtemp[row];
                        val = x - bf2f(f2bf(x));
                    }
                }
                pk.u[i] = f2bf(val);
            }
            *(s16x8*)(o + kc) = pk.v;
        }
    } else if (bid < NBLK_A + NBLK_B) {
        int v = (bid - NBLK_A) * 256 + t;
        bool valid = v < VV;
        unsigned short* o = lbswB + (size_t)v * K2;
        union { s16x8 v8; unsigned short u[8]; } pk;
#pragma unroll
        for (int g = 0; g < 3; ++g) {
#pragma unroll
            for (int i = 0; i < 8; ++i)
                pk.u[i] = valid ? f2bf(lbsw[(size_t)v * NJ + g * 8 + i]) : (unsigned short)0;
            *(s16x8*)(o + g * 8) = pk.v8;
        }
#pragma unroll
        for (int i = 0; i < 8; ++i) pk.u[i] = 0;
        *(s16x8*)(o + 24) = pk.v8;
    } else {
        int idx = bid - NBLK_A - NBLK_B;
        int j  = idx / NCH;
        int ch = idx % NCH;
        int v0 = ch * CHV;
        int vend = min(VV, v0 + CHV);

        float acc[33];
#pragma unroll
        for (int i = 0; i < 33; ++i) acc[i] = 0.f;

        for (int v = v0 + t; v < vend; v += 256) {
            float w = Jreg[(size_t)j * VV + v];
#pragma unroll
            for (int c = 0; c < 3; ++c) {
                acc[30 + c] += w * vtemp[v * 3 + c];
#pragma unroll
                for (int l = 0; l < NBETA; ++l)
                    acc[c * NBETA + l] += w * sdirs[(size_t)(v * 3 + c) * NBETA + l];
            }
        }
#pragma unroll
        for (int i = 0; i < 33; ++i) {
            float x = acc[i];
            for (int off = 32; off > 0; off >>= 1) x += __shfl_down(x, off);
            acc[i] = x;
        }
        __shared__ float sred[33][4];
        int wave = t >> 6, lane = t & 63;
        if (lane == 0) {
#pragma unroll
            for (int i = 0; i < 33; ++i) sred[i][wave] = acc[i];
        }
        __syncthreads();
        if (t == 0) {
#pragma unroll
            for (int i = 0; i < 33; ++i)
                jpart[(size_t)(j * NCH + ch) * 33 + i] =
                    sred[i][0] + sred[i][1] + sred[i][2] + sred[i][3];
        }
    }
}

// ---------------------------------------------------------------------------
// k_batch: jpart reduce (in-block) -> rodrigues, kinematic chain,
// pose features -> pfB (bf16), rel transforms -> relBT (bf16 GEMM2 B rows),
// posed joints -> out.
// ---------------------------------------------------------------------------
__global__ __launch_bounds__(32) void k_batch(
    const float* __restrict__ transl,
    const float* __restrict__ orient,
    const float* __restrict__ betas,
    const float* __restrict__ bpose,
    const float* __restrict__ jpart,     // (24, NCH, 33)
    unsigned short* __restrict__ pfB,    // (B, KP)
    unsigned short* __restrict__ relBT,  // (B*12, K2)
    float* __restrict__ joints_out)      // (B, 24, 3)
{
    int t = threadIdx.x;
    int b = blockIdx.x * 32 + t;

    __shared__ float sJ[NJ * 33];
    __shared__ float chain[NJ][12][32];

    for (int idx = t; idx < NJ * 33; idx += 32) {
        int j = idx / 33, i = idx % 33;
        float s = 0.f;
#pragma unroll
        for (int c = 0; c < NCH; ++c) s += jpart[(size_t)(j * NCH + c) * 33 + i];
        sJ[idx] = s;
    }
    __syncthreads();

    float bet[NBETA];
#pragma unroll
    for (int l = 0; l < NBETA; ++l) bet[l] = betas[b * NBETA + l];

    float jx[NJ], jy[NJ], jz[NJ];
#pragma unroll
    for (int j = 0; j < NJ; ++j) {
        float a = sJ[j * 33 + 30], bb = sJ[j * 33 + 31], cc = sJ[j * 33 + 32];
#pragma unroll
        for (int l = 0; l < NBETA; ++l) {
            a  += sJ[j * 33 + l]      * bet[l];
            bb += sJ[j * 33 + 10 + l] * bet[l];
            cc += sJ[j * 33 + 20 + l] * bet[l];
        }
        jx[j] = a; jy[j] = bb; jz[j] = cc;
    }

    float tr0 = transl[b * 3 + 0], tr1 = transl[b * 3 + 1], tr2 = transl[b * 3 + 2];

    for (int j = 0; j < NJ; ++j) {
        float rx, ry, rz;
        if (j == 0) {
            rx = orient[b * 3 + 0]; ry = orient[b * 3 + 1]; rz = orient[b * 3 + 2];
        } else {
            rx = bpose[b * 69 + (j - 1) * 3 + 0];
            ry = bpose[b * 69 + (j - 1) * 3 + 1];
            rz = bpose[b * 69 + (j - 1) * 3 + 2];
        }
        float ax = rx + 1e-8f, ay = ry + 1e-8f, az = rz + 1e-8f;
        float angle = sqrtf(ax * ax + ay * ay + az * az);
        float inv = 1.f / angle;
        float kx = rx * inv, ky = ry * inv, kz = rz * inv;
        float s = sinf(angle), c = cosf(angle), omc = 1.f - c;
        float R[9];
        R[0] = 1.f - omc * (ky * ky + kz * kz);
        R[1] = -s * kz + omc * (kx * ky);
        R[2] =  s * ky + omc * (kx * kz);
        R[3] =  s * kz + omc * (kx * ky);
        R[4] = 1.f - omc * (kx * kx + kz * kz);
        R[5] = -s * kx + omc * (ky * kz);
        R[6] = -s * ky + omc * (kx * kz);
        R[7] =  s * kx + omc * (ky * kz);
        R[8] = 1.f - omc * (kx * kx + ky * ky);

        if (j > 0) {
#pragma unroll
            for (int e = 0; e < 9; ++e) {
                float val = R[e] - ((e == 0 || e == 4 || e == 8) ? 1.f : 0.f);
                pfB[(size_t)b * KP + (j - 1) * 9 + e] = f2bf(val);
            }
        }

        int p = kParents[j];
        float tx, ty, tz;
        if (j == 0) { tx = jx[0]; ty = jy[0]; tz = jz[0]; }
        else        { tx = jx[j] - jx[p]; ty = jy[j] - jy[p]; tz = jz[j] - jz[p]; }

        float A[12];
        if (j == 0) {
            A[0] = R[0]; A[1] = R[1]; A[2]  = R[2]; A[3]  = tx;
            A[4] = R[3]; A[5] = R[4]; A[6]  = R[5]; A[7]  = ty;
            A[8] = R[6]; A[9] = R[7]; A[10] = R[8]; A[11] = tz;
        } else {
            float P[12];
#pragma unroll
            for (int e = 0; e < 12; ++e) P[e] = chain[p][e][t];
#pragma unroll
            for (int r = 0; r < 3; ++r) {
#pragma unroll
                for (int cc = 0; cc < 3; ++cc)
                    A[r * 4 + cc] = P[r * 4 + 0] * R[0 * 3 + cc] +
                                    P[r * 4 + 1] * R[1 * 3 + cc] +
                                    P[r * 4 + 2] * R[2 * 3 + cc];
                A[r * 4 + 3] = P[r * 4 + 0] * tx + P[r * 4 + 1] * ty +
                               P[r * 4 + 2] * tz + P[r * 4 + 3];
            }
        }
#pragma unroll
        for (int e = 0; e < 12; ++e) chain[j][e][t] = A[e];

        joints_out[(b * NJ + j) * 3 + 0] = A[3]  + tr0;
        joints_out[(b * NJ + j) * 3 + 1] = A[7]  + tr1;
        joints_out[(b * NJ + j) * 3 + 2] = A[11] + tr2;

        float bx = A[0] * jx[j] + A[1] * jy[j] + A[2]  * jz[j];
        float by = A[4] * jx[j] + A[5] * jy[j] + A[6]  * jz[j];
        float bz = A[8] * jx[j] + A[9] * jy[j] + A[10] * jz[j];
        float relv[12];
        relv[0] = A[0]; relv[1] = A[1]; relv[2]  = A[2];  relv[3]  = A[3]  - bx;
        relv[4] = A[4]; relv[5] = A[5]; relv[6]  = A[6];  relv[7]  = A[7]  - by;
        relv[8] = A[8]; relv[9] = A[9]; relv[10] = A[10]; relv[11] = A[11] - bz;
#pragma unroll
        for (int e = 0; e < 12; ++e)
            relBT[(size_t)(b * 12 + e) * K2 + j] = f2bf(relv[e]);
    }

    // zero pad relBT cols 24..31
#pragma unroll
    for (int e = 0; e < 12; ++e)
#pragma unroll
        for (int j2 = NJ; j2 < K2; ++j2)
            relBT[(size_t)(b * 12 + e) * K2 + j2] = 0;

    // pfB tail: betas, ones (vtemp hi/lo), zero pad
#pragma unroll
    for (int l = 0; l < NBETA; ++l)
        pfB[(size_t)b * KP + PF + l] = f2bf(bet[l]);
    pfB[(size_t)b * KP + PF + NBETA]     = 0x3F80;
    pfB[(size_t)b * KP + PF + NBETA + 1] = 0x3F80;
    for (int k = PF + NBETA + 2; k < KP; ++k) pfB[(size_t)b * KP + k] = 0;
}

// ---------------------------------------------------------------------------
// k_main: block = 64 verts x 16 batches, 256 thr (4 waves), 4 blocks/CU.
// GEMM1 (MFMA): x[v3][b] = v_posed -> xls fp32 (stride 19, conflict-free read)
// GEMM2 (MFMA): T[be][v] -> Tls bf16 (stride 68, packed 8B stores), wave-local
// Epilogue: out = T*[x,1] + transl; wave w handles batches 4w..4w+3.
// ---------------------------------------------------------------------------
__global__ __launch_bounds__(256, 4) void k_main(
    const unsigned short* __restrict__ pdT,    // (V3PAD, KP)
    const unsigned short* __restrict__ pfB,    // (BB, KP)
    const unsigned short* __restrict__ lbswB,  // (VPAD, K2)
    const unsigned short* __restrict__ relBT,  // (BB*12, K2)
    const float* __restrict__ transl,          // (B,3)
    float* __restrict__ verts)                 // (B,V,3)
{
    int bt = blockIdx.x;            // batch tile 0..63
    int vt = blockIdx.y;            // vert tile 0..107
    int t  = threadIdx.x;
    int lane = t & 63;
    int w    = t >> 6;
    int b0   = bt * 16;
    int v3base = vt * M3;

    __shared__ float xls[M3 * XS];              // 14592 B
    __shared__ unsigned short Tls[192 * TS];    // 26112 B

    int lr  = lane & 15;
    int hi2 = lane >> 4;
    int lk  = hi2 * 8;

    // ---- GEMM1 ----
    {
        f32x4 acc0 = {0.f,0.f,0.f,0.f};
        f32x4 acc1 = {0.f,0.f,0.f,0.f};
        f32x4 acc2 = {0.f,0.f,0.f,0.f};
        const unsigned short* pa = pdT + (size_t)(v3base + w * 48 + lr) * KP + lk;
        const unsigned short* pb = pfB + (size_t)(b0 + lr) * KP + lk;
#pragma unroll
        for (int ks = 0; ks < KP / 32; ++ks) {
            s16x8 bf = *(const s16x8*)(pb + ks * 32);
            s16x8 a0 = *(const s16x8*)(pa + ks * 32);
            s16x8 a1 = *(const s16x8*)(pa + (size_t)16 * KP + ks * 32);
            s16x8 a2 = *(const s16x8*)(pa + (size_t)32 * KP + ks * 32);
            acc0 = __builtin_amdgcn_mfma_f32_16x16x32_bf16(a0, bf, acc0, 0, 0, 0);
            acc1 = __builtin_amdgcn_mfma_f32_16x16x32_bf16(a1, bf, acc1, 0, 0, 0);
            acc2 = __builtin_amdgcn_mfma_f32_16x16x32_bf16(a2, bf, acc2, 0, 0, 0);
        }
        int rbase = w * 48 + hi2 * 4;
#pragma unroll
        for (int r = 0; r < 4; ++r) {
            xls[(rbase + r) * XS + lr]      = acc0[r];
            xls[(rbase + 16 + r) * XS + lr] = acc1[r];
            xls[(rbase + 32 + r) * XS + lr] = acc2[r];
        }
    }

    // ---- GEMM2: wave w computes be range [48w, 48w+48) = batches 4w..4w+3 ----
    {
        s16x8 af[4];
        const unsigned short* la = lbswB + (size_t)(vt * VTB + lr) * K2 + lk;
#pragma unroll
        for (int m = 0; m < 4; ++m)
            af[m] = *(const s16x8*)(la + (size_t)m * 16 * K2);

#pragma unroll
        for (int i = 0; i < 3; ++i) {
            int nt = w * 3 + i;
            const unsigned short* lb = relBT + (size_t)(b0 * 12 + nt * 16 + lr) * K2 + lk;
            s16x8 bf0 = *(const s16x8*)(lb);
            int be = nt * 16 + lr;
#pragma unroll
            for (int m = 0; m < 4; ++m) {
                f32x4 acc = {0.f,0.f,0.f,0.f};
                acc = __builtin_amdgcn_mfma_f32_16x16x32_bf16(af[m], bf0, acc, 0, 0, 0);
                int vb = m * 16 + hi2 * 4;
                union { s16x4 v4; unsigned short u[4]; } pk;
#pragma unroll
                for (int r = 0; r < 4; ++r) pk.u[r] = f2bf(acc[r]);
                *(s16x4*)(&Tls[be * TS + vb]) = pk.v4;
            }
        }
    }

    __syncthreads();

    // ---- epilogue ----
    int v = vt * VTB + lane;
    if (v < VV) {
#pragma unroll
        for (int q = 0; q < 4; ++q) {
            int brl = w * 4 + q;                   // wave-local batch
            int bu  = __builtin_amdgcn_readfirstlane(b0 + brl);

            float x0 = xls[(3 * lane + 0) * XS + brl];
            float x1 = xls[(3 * lane + 1) * XS + brl];
            float x2 = xls[(3 * lane + 2) * XS + brl];

            float T[12];
#pragma unroll
            for (int e = 0; e < 12; ++e)
                T[e] = bf2f(Tls[(brl * 12 + e) * TS + lane]);

            float o0 = T[0] * x0 + T[1] * x1 + T[2]  * x2 + T[3]  + transl[(size_t)bu * 3 + 0];
            float o1 = T[4] * x0 + T[5] * x1 + T[6]  * x2 + T[7]  + transl[(size_t)bu * 3 + 1];
            float o2 = T[8] * x0 + T[9] * x1 + T[10] * x2 + T[11] + transl[(size_t)bu * 3 + 2];

            float* o = verts + ((size_t)(b0 + brl) * VV + v) * 3;
            o[0] = o0; o[1] = o1; o[2] = o2;
        }
    }
}

extern "C" void kernel_launch(void* const* d_in, const int* in_sizes, int n_in,
                              void* d_out, int out_size, void* d_ws, size_t ws_size,
                              hipStream_t stream) {
    const float* transl = (const float*)d_in[0];
    const float* orient = (const float*)d_in[1];
    const float* betas  = (const float*)d_in[2];
    const float* bpose  = (const float*)d_in[3];
    const float* vtemp  = (const float*)d_in[4];
    const float* sdirs  = (const float*)d_in[5];
    const float* pdirs  = (const float*)d_in[6];
    const float* jreg   = (const float*)d_in[7];
    const float* lbsw   = (const float*)d_in[8];

    float* out = (float*)d_out;
    float* verts_out  = out;
    float* joints_out = out + (size_t)BB * VV * 3;

    float* ws    = (float*)d_ws;
    float* jpart = ws;                                   // 24*8*33 = 6336 f
    unsigned short* pfB   = (unsigned short*)(ws + 6336);      // B*KP
    unsigned short* pdT   = pfB + (size_t)BB * KP;             // V3PAD*KP
    unsigned short* lbswB = pdT + (size_t)V3PAD * KP;          // VPAD*K2
    unsigned short* relBT = lbswB + (size_t)VPAD * K2;         // B*12*K2

    k_prep_all<<<NBLK_A + NBLK_B + NBLK_C, 256, 0, stream>>>(
        pdirs, sdirs, vtemp, lbsw, jreg, pdT, lbswB, jpart);
    k_batch<<<BB / 32, 32, 0, stream>>>(transl, orient, betas, bpose,
                                        jpart, pfB, relBT, joints_out);
    dim3 g(BB / 16, NVT);
    k_main<<<g, 256, 0, stream>>>(pdT, pfB, lbswB, relBT, transl, verts_out);
}

// Round 7
// 125.015 us; speedup vs baseline: 18.2072x; 1.0645x over previous
//
#include <hip/hip_runtime.h>

#define BB 1024
#define VV 6890
#define NJ 24
#define NBETA 10
#define PF 207            // (J-1)*9
#define V3 (VV*3)         // 20670
#define KP 224            // GEMM1 K: 207 pose + 10 shape + 2 vtemp(hi/lo) + 5 zero
#define VTB 64            // vertices per block tile in k_main
#define M3 (VTB*3)        // 192 v3-rows per tile
#define NVT ((VV + VTB - 1) / VTB)   // 108
#define V3PAD (NVT * VTB * 3)        // 20736 rows in pdT
#define VPAD (NVT * VTB)             // 6912 rows in lbswB
#define K2 32             // GEMM2 K: 24 joints + 1 transl-one + 7 zero
#define NCH 8             // jreg chunks
#define CHV 862           // ceil(VV/NCH)
#define NBLK_A ((V3PAD / 256) * 4)   // 324 (4-way k-split)
#define NBLK_B (VPAD / 256)          // 27
#define NBLK_C (NJ * NCH)            // 192
#define XS2 196           // xls stride (dwords), layout [b][v3local]
#define TS2 196           // Tls stride (u16),   layout [v][be]

typedef float f32x4 __attribute__((ext_vector_type(4)));
typedef short s16x8 __attribute__((ext_vector_type(8)));
typedef short s16x4 __attribute__((ext_vector_type(4)));

__device__ __constant__ int kParents[NJ] = {-1,0,0,0,1,2,3,4,5,6,7,8,9,9,9,12,13,14,16,17,18,19,20,21};

__device__ __forceinline__ unsigned short f2bf(float x) {
    unsigned int u = __float_as_uint(x);
    unsigned int r = (u + 0x7fffu + ((u >> 16) & 1u)) >> 16;
    return (unsigned short)r;
}
__device__ __forceinline__ float bf2f(unsigned short h) {
    return __uint_as_float((unsigned int)h << 16);
}

// ---------------------------------------------------------------------------
// k_prep_all: 3 block-ranges:
//  A [0,324):     pdT rows (4-way k-split) — GEMM1 A (posedirs|sdirs|vtemp|0)
//  B [324,351):   lbswB rows — GEMM2 B (w(24) | 1.0 | 0(7))
//  C [351,543):   jreg partials (24 joints x 8 chunks)
// ---------------------------------------------------------------------------
__global__ __launch_bounds__(256) void k_prep_all(
    const float* __restrict__ pdirs,     // (207, V3)
    const float* __restrict__ sdirs,     // (V3, 10)
    const float* __restrict__ vtemp,     // (V3)
    const float* __restrict__ lbsw,      // (V, 24)
    const float* __restrict__ Jreg,      // (24, V)
    unsigned short* __restrict__ pdT,    // (V3PAD, KP)
    unsigned short* __restrict__ lbswB,  // (VPAD, K2)
    float* __restrict__ jpart)           // (24, NCH, 33)
{
    int bid = blockIdx.x;
    int t = threadIdx.x;

    if (bid < NBLK_A) {
        int ra = bid >> 2;
        int kq = bid & 3;
        int row = ra * 256 + t;
        bool valid = row < V3;
        unsigned short* o = pdT + (size_t)row * KP;
        for (int kc = kq * 56; kc < kq * 56 + 56; kc += 8) {
            union { s16x8 v; unsigned short u[8]; } pk;
#pragma unroll
            for (int i = 0; i < 8; ++i) {
                int k = kc + i;
                float val = 0.f;
                if (valid) {
                    if (k < PF)                val = pdirs[(size_t)k * V3 + row];
                    else if (k < PF + NBETA)   val = sdirs[(size_t)row * NBETA + (k - PF)];
                    else if (k == PF + NBETA)  val = vtemp[row];
                    else if (k == PF + NBETA + 1) {
                        float x = vtemp[row];
                        val = x - bf2f(f2bf(x));
                    }
                }
                pk.u[i] = f2bf(val);
            }
            *(s16x8*)(o + kc) = pk.v;
        }
    } else if (bid < NBLK_A + NBLK_B) {
        int v = (bid - NBLK_A) * 256 + t;
        bool valid = v < VV;
        unsigned short* o = lbswB + (size_t)v * K2;
        union { s16x8 v8; unsigned short u[8]; } pk;
#pragma unroll
        for (int g = 0; g < 3; ++g) {
#pragma unroll
            for (int i = 0; i < 8; ++i)
                pk.u[i] = valid ? f2bf(lbsw[(size_t)v * NJ + g * 8 + i]) : (unsigned short)0;
            *(s16x8*)(o + g * 8) = pk.v8;
        }
        // col 24 = 1.0 (transl K-column), 25..31 = 0
        pk.u[0] = 0x3F80;
#pragma unroll
        for (int i = 1; i < 8; ++i) pk.u[i] = 0;
        *(s16x8*)(o + 24) = pk.v8;
    } else {
        int idx = bid - NBLK_A - NBLK_B;
        int j  = idx / NCH;
        int ch = idx % NCH;
        int v0 = ch * CHV;
        int vend = min(VV, v0 + CHV);

        float acc[33];
#pragma unroll
        for (int i = 0; i < 33; ++i) acc[i] = 0.f;

        for (int v = v0 + t; v < vend; v += 256) {
            float w = Jreg[(size_t)j * VV + v];
#pragma unroll
            for (int c = 0; c < 3; ++c) {
                acc[30 + c] += w * vtemp[v * 3 + c];
#pragma unroll
                for (int l = 0; l < NBETA; ++l)
                    acc[c * NBETA + l] += w * sdirs[(size_t)(v * 3 + c) * NBETA + l];
            }
        }
#pragma unroll
        for (int i = 0; i < 33; ++i) {
            float x = acc[i];
            for (int off = 32; off > 0; off >>= 1) x += __shfl_down(x, off);
            acc[i] = x;
        }
        __shared__ float sred[33][4];
        int wave = t >> 6, lane = t & 63;
        if (lane == 0) {
#pragma unroll
            for (int i = 0; i < 33; ++i) sred[i][wave] = acc[i];
        }
        __syncthreads();
        if (t == 0) {
#pragma unroll
            for (int i = 0; i < 33; ++i)
                jpart[(size_t)(j * NCH + ch) * 33 + i] =
                    sred[i][0] + sred[i][1] + sred[i][2] + sred[i][3];
        }
    }
}

// ---------------------------------------------------------------------------
// k_batch: jpart reduce -> rodrigues, kinematic chain, pose features -> pfB,
// rel transforms (+transl in col 24) -> relBT, posed joints -> out.
// ---------------------------------------------------------------------------
__global__ __launch_bounds__(32) void k_batch(
    const float* __restrict__ transl,
    const float* __restrict__ orient,
    const float* __restrict__ betas,
    const float* __restrict__ bpose,
    const float* __restrict__ jpart,     // (24, NCH, 33)
    unsigned short* __restrict__ pfB,    // (B, KP)
    unsigned short* __restrict__ relBT,  // (B*12, K2)
    float* __restrict__ joints_out)      // (B, 24, 3)
{
    int t = threadIdx.x;
    int b = blockIdx.x * 32 + t;

    __shared__ float sJ[NJ * 33];
    __shared__ float chain[NJ][12][32];

    for (int idx = t; idx < NJ * 33; idx += 32) {
        int j = idx / 33, i = idx % 33;
        float s = 0.f;
#pragma unroll
        for (int c = 0; c < NCH; ++c) s += jpart[(size_t)(j * NCH + c) * 33 + i];
        sJ[idx] = s;
    }
    __syncthreads();

    float bet[NBETA];
#pragma unroll
    for (int l = 0; l < NBETA; ++l) bet[l] = betas[b * NBETA + l];

    float jx[NJ], jy[NJ], jz[NJ];
#pragma unroll
    for (int j = 0; j < NJ; ++j) {
        float a = sJ[j * 33 + 30], bb = sJ[j * 33 + 31], cc = sJ[j * 33 + 32];
#pragma unroll
        for (int l = 0; l < NBETA; ++l) {
            a  += sJ[j * 33 + l]      * bet[l];
            bb += sJ[j * 33 + 10 + l] * bet[l];
            cc += sJ[j * 33 + 20 + l] * bet[l];
        }
        jx[j] = a; jy[j] = bb; jz[j] = cc;
    }

    float tr0 = transl[b * 3 + 0], tr1 = transl[b * 3 + 1], tr2 = transl[b * 3 + 2];

    for (int j = 0; j < NJ; ++j) {
        float rx, ry, rz;
        if (j == 0) {
            rx = orient[b * 3 + 0]; ry = orient[b * 3 + 1]; rz = orient[b * 3 + 2];
        } else {
            rx = bpose[b * 69 + (j - 1) * 3 + 0];
            ry = bpose[b * 69 + (j - 1) * 3 + 1];
            rz = bpose[b * 69 + (j - 1) * 3 + 2];
        }
        float ax = rx + 1e-8f, ay = ry + 1e-8f, az = rz + 1e-8f;
        float angle = sqrtf(ax * ax + ay * ay + az * az);
        float inv = 1.f / angle;
        float kx = rx * inv, ky = ry * inv, kz = rz * inv;
        float s = sinf(angle), c = cosf(angle), omc = 1.f - c;
        float R[9];
        R[0] = 1.f - omc * (ky * ky + kz * kz);
        R[1] = -s * kz + omc * (kx * ky);
        R[2] =  s * ky + omc * (kx * kz);
        R[3] =  s * kz + omc * (kx * ky);
        R[4] = 1.f - omc * (kx * kx + kz * kz);
        R[5] = -s * kx + omc * (ky * kz);
        R[6] = -s * ky + omc * (kx * kz);
        R[7] =  s * kx + omc * (ky * kz);
        R[8] = 1.f - omc * (kx * kx + ky * ky);

        if (j > 0) {
#pragma unroll
            for (int e = 0; e < 9; ++e) {
                float val = R[e] - ((e == 0 || e == 4 || e == 8) ? 1.f : 0.f);
                pfB[(size_t)b * KP + (j - 1) * 9 + e] = f2bf(val);
            }
        }

        int p = kParents[j];
        float tx, ty, tz;
        if (j == 0) { tx = jx[0]; ty = jy[0]; tz = jz[0]; }
        else        { tx = jx[j] - jx[p]; ty = jy[j] - jy[p]; tz = jz[j] - jz[p]; }

        float A[12];
        if (j == 0) {
            A[0] = R[0]; A[1] = R[1]; A[2]  = R[2]; A[3]  = tx;
            A[4] = R[3]; A[5] = R[4]; A[6]  = R[5]; A[7]  = ty;
            A[8] = R[6]; A[9] = R[7]; A[10] = R[8]; A[11] = tz;
        } else {
            float P[12];
#pragma unroll
            for (int e = 0; e < 12; ++e) P[e] = chain[p][e][t];
#pragma unroll
            for (int r = 0; r < 3; ++r) {
#pragma unroll
                for (int cc = 0; cc < 3; ++cc)
                    A[r * 4 + cc] = P[r * 4 + 0] * R[0 * 3 + cc] +
                                    P[r * 4 + 1] * R[1 * 3 + cc] +
                                    P[r * 4 + 2] * R[2 * 3 + cc];
                A[r * 4 + 3] = P[r * 4 + 0] * tx + P[r * 4 + 1] * ty +
                               P[r * 4 + 2] * tz + P[r * 4 + 3];
            }
        }
#pragma unroll
        for (int e = 0; e < 12; ++e) chain[j][e][t] = A[e];

        joints_out[(b * NJ + j) * 3 + 0] = A[3]  + tr0;
        joints_out[(b * NJ + j) * 3 + 1] = A[7]  + tr1;
        joints_out[(b * NJ + j) * 3 + 2] = A[11] + tr2;

        float bx = A[0] * jx[j] + A[1] * jy[j] + A[2]  * jz[j];
        float by = A[4] * jx[j] + A[5] * jy[j] + A[6]  * jz[j];
        float bz = A[8] * jx[j] + A[9] * jy[j] + A[10] * jz[j];
        float relv[12];
        relv[0] = A[0]; relv[1] = A[1]; relv[2]  = A[2];  relv[3]  = A[3]  - bx;
        relv[4] = A[4]; relv[5] = A[5]; relv[6]  = A[6];  relv[7]  = A[7]  - by;
        relv[8] = A[8]; relv[9] = A[9]; relv[10] = A[10]; relv[11] = A[11] - bz;
#pragma unroll
        for (int e = 0; e < 12; ++e)
            relBT[(size_t)(b * 12 + e) * K2 + j] = f2bf(relv[e]);
    }

    // relBT tail: col 24 = transl component (paired with lbswB col24 = 1.0)
#pragma unroll
    for (int e = 0; e < 12; ++e) {
        float tv = (e == 3) ? tr0 : (e == 7) ? tr1 : (e == 11) ? tr2 : 0.f;
        relBT[(size_t)(b * 12 + e) * K2 + 24] = f2bf(tv);
#pragma unroll
        for (int j2 = NJ + 1; j2 < K2; ++j2)
            relBT[(size_t)(b * 12 + e) * K2 + j2] = 0;
    }

    // pfB tail: betas, ones (vtemp hi/lo), zero pad
#pragma unroll
    for (int l = 0; l < NBETA; ++l)
        pfB[(size_t)b * KP + PF + l] = f2bf(bet[l]);
    pfB[(size_t)b * KP + PF + NBETA]     = 0x3F80;
    pfB[(size_t)b * KP + PF + NBETA + 1] = 0x3F80;
    for (int k = PF + NBETA + 2; k < KP; ++k) pfB[(size_t)b * KP + k] = 0;
}

// ---------------------------------------------------------------------------
// k_main: block = 64 verts x 16 batches, 256 thr (4 waves), 4 blocks/CU.
// GEMM1: x -> xls [b][v3l] (b128 writes, b64+b32 reads)
// GEMM2 (swapped A=relBT, B=lbswB): D[be][v] -> Tls [v][be] bf16 (b64 writes,
// b64 reads). transl folded via K-col 24. Epilogue: 12 FMA + 3 stores.
// ---------------------------------------------------------------------------
__global__ __launch_bounds__(256, 4) void k_main(
    const unsigned short* __restrict__ pdT,    // (V3PAD, KP)
    const unsigned short* __restrict__ pfB,    // (BB, KP)
    const unsigned short* __restrict__ lbswB,  // (VPAD, K2)
    const unsigned short* __restrict__ relBT,  // (BB*12, K2)
    float* __restrict__ verts)                 // (B,V,3)
{
    int bt = blockIdx.x;            // batch tile 0..63
    int vt = blockIdx.y;            // vert tile 0..107
    int t  = threadIdx.x;
    int lane = t & 63;
    int w    = t >> 6;
    int b0   = bt * 16;
    int v3base = vt * M3;

    __shared__ float xls[16 * XS2];             // 12544 B, [b][v3l]
    __shared__ unsigned short Tls[64 * TS2];    // 25088 B, [v][be]

    int lr  = lane & 15;
    int hi2 = lane >> 4;
    int lk  = hi2 * 8;

    // ---- GEMM1: x[v3][b] ----
    {
        f32x4 acc[3];
#pragma unroll
        for (int s = 0; s < 3; ++s) acc[s] = (f32x4){0.f,0.f,0.f,0.f};
        const unsigned short* pa = pdT + (size_t)(v3base + w * 48 + lr) * KP + lk;
        const unsigned short* pb = pfB + (size_t)(b0 + lr) * KP + lk;
#pragma unroll
        for (int ks = 0; ks < KP / 32; ++ks) {
            s16x8 bf = *(const s16x8*)(pb + ks * 32);
#pragma unroll
            for (int s = 0; s < 3; ++s) {
                s16x8 a = *(const s16x8*)(pa + (size_t)(s * 16) * KP + ks * 32);
                acc[s] = __builtin_amdgcn_mfma_f32_16x16x32_bf16(a, bf, acc[s], 0, 0, 0);
            }
        }
        // D: col(lane&15)=b, row(hi2*4+r)=v3-sub -> xls[b][v3l], r contiguous
#pragma unroll
        for (int s = 0; s < 3; ++s)
            *(f32x4*)&xls[lr * XS2 + w * 48 + s * 16 + hi2 * 4] = acc[s];
    }

    // ---- GEMM2 (swapped): T[be][v], wave w owns be in [48w, 48w+48) ----
    {
        s16x8 rf[3], lf[4];
        const unsigned short* pr = relBT + (size_t)(b0 * 12 + w * 48 + lr) * K2 + lk;
#pragma unroll
        for (int mt = 0; mt < 3; ++mt)
            rf[mt] = *(const s16x8*)(pr + (size_t)(mt * 16) * K2);
        const unsigned short* pl = lbswB + (size_t)(vt * VTB + lr) * K2 + lk;
#pragma unroll
        for (int nt = 0; nt < 4; ++nt)
            lf[nt] = *(const s16x8*)(pl + (size_t)(nt * 16) * K2);

#pragma unroll
        for (int nt = 0; nt < 4; ++nt) {
            int vrow = nt * 16 + lr;
#pragma unroll
            for (int mt = 0; mt < 3; ++mt) {
                f32x4 a2 = {0.f,0.f,0.f,0.f};
                a2 = __builtin_amdgcn_mfma_f32_16x16x32_bf16(rf[mt], lf[nt], a2, 0, 0, 0);
                // D: col(lane&15)=v-sub, row(hi2*4+r)=be-sub, r contiguous be
                union { s16x4 v4; unsigned short u[4]; } pk;
#pragma unroll
                for (int r = 0; r < 4; ++r) pk.u[r] = f2bf(a2[r]);
                *(s16x4*)&Tls[vrow * TS2 + w * 48 + mt * 16 + hi2 * 4] = pk.v4;
            }
        }
    }

    __syncthreads();

    // ---- epilogue: wave w handles batches 4w..4w+3, vertex = lane ----
    int v = vt * VTB + lane;
    if (v < VV) {
#pragma unroll
        for (int q = 0; q < 4; ++q) {
            int brl = w * 4 + q;

            const float* xp = &xls[brl * XS2 + 3 * lane];
            float x0 = xp[0], x1 = xp[1], x2 = xp[2];

            const unsigned short* tp = &Tls[lane * TS2 + w * 48 + q * 12];
            uint2 dA = *(const uint2*)tp;
            uint2 dB = *(const uint2*)(tp + 4);
            uint2 dC = *(const uint2*)(tp + 8);
            float T0  = __uint_as_float(dA.x << 16);
            float T1  = __uint_as_float(dA.x & 0xffff0000u);
            float T2  = __uint_as_float(dA.y << 16);
            float T3  = __uint_as_float(dA.y & 0xffff0000u);
            float T4  = __uint_as_float(dB.x << 16);
            float T5  = __uint_as_float(dB.x & 0xffff0000u);
            float T6  = __uint_as_float(dB.y << 16);
            float T7  = __uint_as_float(dB.y & 0xffff0000u);
            float T8  = __uint_as_float(dC.x << 16);
            float T9  = __uint_as_float(dC.x & 0xffff0000u);
            float T10 = __uint_as_float(dC.y << 16);
            float T11 = __uint_as_float(dC.y & 0xffff0000u);

            float o0 = T0 * x0 + T1 * x1 + T2  * x2 + T3;
            float o1 = T4 * x0 + T5 * x1 + T6  * x2 + T7;
            float o2 = T8 * x0 + T9 * x1 + T10 * x2 + T11;

            float* o = verts + ((size_t)(b0 + brl) * VV + v) * 3;
            o[0] = o0; o[1] = o1; o[2] = o2;
        }
    }
}

extern "C" void kernel_launch(void* const* d_in, const int* in_sizes, int n_in,
                              void* d_out, int out_size, void* d_ws, size_t ws_size,
                              hipStream_t stream) {
    const float* transl = (const float*)d_in[0];
    const float* orient = (const float*)d_in[1];
    const float* betas  = (const float*)d_in[2];
    const float* bpose  = (const float*)d_in[3];
    const float* vtemp  = (const float*)d_in[4];
    const float* sdirs  = (const float*)d_in[5];
    const float* pdirs  = (const float*)d_in[6];
    const float* jreg   = (const float*)d_in[7];
    const float* lbsw   = (const float*)d_in[8];

    float* out = (float*)d_out;
    float* verts_out  = out;
    float* joints_out = out + (size_t)BB * VV * 3;

    float* ws    = (float*)d_ws;
    float* jpart = ws;                                   // 6336 f
    unsigned short* pfB   = (unsigned short*)(ws + 6336);      // B*KP
    unsigned short* pdT   = pfB + (size_t)BB * KP;             // V3PAD*KP
    unsigned short* lbswB = pdT + (size_t)V3PAD * KP;          // VPAD*K2
    unsigned short* relBT = lbswB + (size_t)VPAD * K2;         // B*12*K2

    k_prep_all<<<NBLK_A + NBLK_B + NBLK_C, 256, 0, stream>>>(
        pdirs, sdirs, vtemp, lbsw, jreg, pdT, lbswB, jpart);
    k_batch<<<BB / 32, 32, 0, stream>>>(transl, orient, betas, bpose,
                                        jpart, pfB, relBT, joints_out);
    dim3 g(BB / 16, NVT);
    k_main<<<g, 256, 0, stream>>>(pdT, pfB, lbswB, relBT, verts_out);
}

// Round 8
// 120.513 us; speedup vs baseline: 18.8874x; 1.0374x over previous
//
#include <hip/hip_runtime.h>

#define BB 1024
#define VV 6890
#define NJ 24
#define NBETA 10
#define PF 207            // (J-1)*9
#define V3 (VV*3)         // 20670
#define KP 224            // GEMM1 K: 207 pose + 10 shape + 2 vtemp(hi/lo) + 5 zero
#define VTB 64            // vertices per block tile in k_main
#define M3 (VTB*3)        // 192 v3-rows per tile
#define NVT ((VV + VTB - 1) / VTB)   // 108
#define V3PAD (NVT * VTB * 3)        // 20736 rows in pdT
#define VPAD (NVT * VTB)             // 6912 rows in lbswB
#define K2 32             // GEMM2 K: 24 joints + 1 transl-one + 7 zero
#define NCH 8             // jreg chunks
#define CHV 862           // ceil(VV/NCH)
#define NBLK_A ((V3PAD / 256) * 4)   // 324 (4-way k-split)
#define NBLK_B (VPAD / 256)          // 27
#define NBLK_C (NJ * NCH)            // 192
#define NBT 4             // batch-tiles per k_main block
#define XSW 17            // xls per-wave stride (dwords)
#define TSW 200           // Tls per-wave stride (u16)

typedef float f32x4 __attribute__((ext_vector_type(4)));
typedef short s16x8 __attribute__((ext_vector_type(8)));
typedef short s16x4 __attribute__((ext_vector_type(4)));

__device__ __constant__ int kParents[NJ] = {-1,0,0,0,1,2,3,4,5,6,7,8,9,9,9,12,13,14,16,17,18,19,20,21};

__device__ __forceinline__ unsigned short f2bf(float x) {
    unsigned int u = __float_as_uint(x);
    unsigned int r = (u + 0x7fffu + ((u >> 16) & 1u)) >> 16;
    return (unsigned short)r;
}
__device__ __forceinline__ float bf2f(unsigned short h) {
    return __uint_as_float((unsigned int)h << 16);
}

// ---------------------------------------------------------------------------
// k_prep_all: 3 block-ranges:
//  A [0,324):     pdT rows (4-way k-split) — GEMM1 A (posedirs|sdirs|vtemp|0)
//  B [324,351):   lbswB rows — GEMM2 B (w(24) | 1.0 | 0(7))
//  C [351,543):   jreg partials (24 joints x 8 chunks)
// ---------------------------------------------------------------------------
__global__ __launch_bounds__(256) void k_prep_all(
    const float* __restrict__ pdirs,     // (207, V3)
    const float* __restrict__ sdirs,     // (V3, 10)
    const float* __restrict__ vtemp,     // (V3)
    const float* __restrict__ lbsw,      // (V, 24)
    const float* __restrict__ Jreg,      // (24, V)
    unsigned short* __restrict__ pdT,    // (V3PAD, KP)
    unsigned short* __restrict__ lbswB,  // (VPAD, K2)
    float* __restrict__ jpart)           // (24, NCH, 33)
{
    int bid = blockIdx.x;
    int t = threadIdx.x;

    if (bid < NBLK_A) {
        int ra = bid >> 2;
        int kq = bid & 3;
        int row = ra * 256 + t;
        bool valid = row < V3;
        unsigned short* o = pdT + (size_t)row * KP;
        for (int kc = kq * 56; kc < kq * 56 + 56; kc += 8) {
            union { s16x8 v; unsigned short u[8]; } pk;
#pragma unroll
            for (int i = 0; i < 8; ++i) {
                int k = kc + i;
                float val = 0.f;
                if (valid) {
                    if (k < PF)                val = pdirs[(size_t)k * V3 + row];
                    else if (k < PF + NBETA)   val = sdirs[(size_t)row * NBETA + (k - PF)];
                    else if (k == PF + NBETA)  val = vtemp[row];
                    else if (k == PF + NBETA + 1) {
                        float x = vtemp[row];
                        val = x - bf2f(f2bf(x));
                    }
                }
                pk.u[i] = f2bf(val);
            }
            *(s16x8*)(o + kc) = pk.v;
        }
    } else if (bid < NBLK_A + NBLK_B) {
        int v = (bid - NBLK_A) * 256 + t;
        bool valid = v < VV;
        unsigned short* o = lbswB + (size_t)v * K2;
        union { s16x8 v8; unsigned short u[8]; } pk;
#pragma unroll
        for (int g = 0; g < 3; ++g) {
#pragma unroll
            for (int i = 0; i < 8; ++i)
                pk.u[i] = valid ? f2bf(lbsw[(size_t)v * NJ + g * 8 + i]) : (unsigned short)0;
            *(s16x8*)(o + g * 8) = pk.v8;
        }
        // col 24 = 1.0 (transl K-column), 25..31 = 0
        pk.u[0] = 0x3F80;
#pragma unroll
        for (int i = 1; i < 8; ++i) pk.u[i] = 0;
        *(s16x8*)(o + 24) = pk.v8;
    } else {
        int idx = bid - NBLK_A - NBLK_B;
        int j  = idx / NCH;
        int ch = idx % NCH;
        int v0 = ch * CHV;
        int vend = min(VV, v0 + CHV);

        float acc[33];
#pragma unroll
        for (int i = 0; i < 33; ++i) acc[i] = 0.f;

        for (int v = v0 + t; v < vend; v += 256) {
            float w = Jreg[(size_t)j * VV + v];
#pragma unroll
            for (int c = 0; c < 3; ++c) {
                acc[30 + c] += w * vtemp[v * 3 + c];
#pragma unroll
                for (int l = 0; l < NBETA; ++l)
                    acc[c * NBETA + l] += w * sdirs[(size_t)(v * 3 + c) * NBETA + l];
            }
        }
#pragma unroll
        for (int i = 0; i < 33; ++i) {
            float x = acc[i];
            for (int off = 32; off > 0; off >>= 1) x += __shfl_down(x, off);
            acc[i] = x;
        }
        __shared__ float sred[33][4];
        int wave = t >> 6, lane = t & 63;
        if (lane == 0) {
#pragma unroll
            for (int i = 0; i < 33; ++i) sred[i][wave] = acc[i];
        }
        __syncthreads();
        if (t == 0) {
#pragma unroll
            for (int i = 0; i < 33; ++i)
                jpart[(size_t)(j * NCH + ch) * 33 + i] =
                    sred[i][0] + sred[i][1] + sred[i][2] + sred[i][3];
        }
    }
}

// ---------------------------------------------------------------------------
// k_batch: jpart reduce -> rodrigues, kinematic chain, pose features -> pfB,
// rel transforms (+transl in col 24) -> relBT, posed joints -> out.
// ---------------------------------------------------------------------------
__global__ __launch_bounds__(32) void k_batch(
    const float* __restrict__ transl,
    const float* __restrict__ orient,
    const float* __restrict__ betas,
    const float* __restrict__ bpose,
    const float* __restrict__ jpart,     // (24, NCH, 33)
    unsigned short* __restrict__ pfB,    // (B, KP)
    unsigned short* __restrict__ relBT,  // (B*12, K2)
    float* __restrict__ joints_out)      // (B, 24, 3)
{
    int t = threadIdx.x;
    int b = blockIdx.x * 32 + t;

    __shared__ float sJ[NJ * 33];
    __shared__ float chain[NJ][12][32];

    for (int idx = t; idx < NJ * 33; idx += 32) {
        int j = idx / 33, i = idx % 33;
        float s = 0.f;
#pragma unroll
        for (int c = 0; c < NCH; ++c) s += jpart[(size_t)(j * NCH + c) * 33 + i];
        sJ[idx] = s;
    }
    __syncthreads();

    float bet[NBETA];
#pragma unroll
    for (int l = 0; l < NBETA; ++l) bet[l] = betas[b * NBETA + l];

    float jx[NJ], jy[NJ], jz[NJ];
#pragma unroll
    for (int j = 0; j < NJ; ++j) {
        float a = sJ[j * 33 + 30], bb = sJ[j * 33 + 31], cc = sJ[j * 33 + 32];
#pragma unroll
        for (int l = 0; l < NBETA; ++l) {
            a  += sJ[j * 33 + l]      * bet[l];
            bb += sJ[j * 33 + 10 + l] * bet[l];
            cc += sJ[j * 33 + 20 + l] * bet[l];
        }
        jx[j] = a; jy[j] = bb; jz[j] = cc;
    }

    float tr0 = transl[b * 3 + 0], tr1 = transl[b * 3 + 1], tr2 = transl[b * 3 + 2];

    for (int j = 0; j < NJ; ++j) {
        float rx, ry, rz;
        if (j == 0) {
            rx = orient[b * 3 + 0]; ry = orient[b * 3 + 1]; rz = orient[b * 3 + 2];
        } else {
            rx = bpose[b * 69 + (j - 1) * 3 + 0];
            ry = bpose[b * 69 + (j - 1) * 3 + 1];
            rz = bpose[b * 69 + (j - 1) * 3 + 2];
        }
        float ax = rx + 1e-8f, ay = ry + 1e-8f, az = rz + 1e-8f;
        float angle = sqrtf(ax * ax + ay * ay + az * az);
        float inv = 1.f / angle;
        float kx = rx * inv, ky = ry * inv, kz = rz * inv;
        float s = sinf(angle), c = cosf(angle), omc = 1.f - c;
        float R[9];
        R[0] = 1.f - omc * (ky * ky + kz * kz);
        R[1] = -s * kz + omc * (kx * ky);
        R[2] =  s * ky + omc * (kx * kz);
        R[3] =  s * kz + omc * (kx * ky);
        R[4] = 1.f - omc * (kx * kx + kz * kz);
        R[5] = -s * kx + omc * (ky * kz);
        R[6] = -s * ky + omc * (kx * kz);
        R[7] =  s * kx + omc * (ky * kz);
        R[8] = 1.f - omc * (kx * kx + ky * ky);

        if (j > 0) {
#pragma unroll
            for (int e = 0; e < 9; ++e) {
                float val = R[e] - ((e == 0 || e == 4 || e == 8) ? 1.f : 0.f);
                pfB[(size_t)b * KP + (j - 1) * 9 + e] = f2bf(val);
            }
        }

        int p = kParents[j];
        float tx, ty, tz;
        if (j == 0) { tx = jx[0]; ty = jy[0]; tz = jz[0]; }
        else        { tx = jx[j] - jx[p]; ty = jy[j] - jy[p]; tz = jz[j] - jz[p]; }

        float A[12];
        if (j == 0) {
            A[0] = R[0]; A[1] = R[1]; A[2]  = R[2]; A[3]  = tx;
            A[4] = R[3]; A[5] = R[4]; A[6]  = R[5]; A[7]  = ty;
            A[8] = R[6]; A[9] = R[7]; A[10] = R[8]; A[11] = tz;
        } else {
            float P[12];
#pragma unroll
            for (int e = 0; e < 12; ++e) P[e] = chain[p][e][t];
#pragma unroll
            for (int r = 0; r < 3; ++r) {
#pragma unroll
                for (int cc = 0; cc < 3; ++cc)
                    A[r * 4 + cc] = P[r * 4 + 0] * R[0 * 3 + cc] +
                                    P[r * 4 + 1] * R[1 * 3 + cc] +
                                    P[r * 4 + 2] * R[2 * 3 + cc];
                A[r * 4 + 3] = P[r * 4 + 0] * tx + P[r * 4 + 1] * ty +
                               P[r * 4 + 2] * tz + P[r * 4 + 3];
            }
        }
#pragma unroll
        for (int e = 0; e < 12; ++e) chain[j][e][t] = A[e];

        joints_out[(b * NJ + j) * 3 + 0] = A[3]  + tr0;
        joints_out[(b * NJ + j) * 3 + 1] = A[7]  + tr1;
        joints_out[(b * NJ + j) * 3 + 2] = A[11] + tr2;

        float bx = A[0] * jx[j] + A[1] * jy[j] + A[2]  * jz[j];
        float by = A[4] * jx[j] + A[5] * jy[j] + A[6]  * jz[j];
        float bz = A[8] * jx[j] + A[9] * jy[j] + A[10] * jz[j];
        float relv[12];
        relv[0] = A[0]; relv[1] = A[1]; relv[2]  = A[2];  relv[3]  = A[3]  - bx;
        relv[4] = A[4]; relv[5] = A[5]; relv[6]  = A[6];  relv[7]  = A[7]  - by;
        relv[8] = A[8]; relv[9] = A[9]; relv[10] = A[10]; relv[11] = A[11] - bz;
#pragma unroll
        for (int e = 0; e < 12; ++e)
            relBT[(size_t)(b * 12 + e) * K2 + j] = f2bf(relv[e]);
    }

    // relBT tail: col 24 = transl component (paired with lbswB col24 = 1.0)
#pragma unroll
    for (int e = 0; e < 12; ++e) {
        float tv = (e == 3) ? tr0 : (e == 7) ? tr1 : (e == 11) ? tr2 : 0.f;
        relBT[(size_t)(b * 12 + e) * K2 + 24] = f2bf(tv);
#pragma unroll
        for (int j2 = NJ + 1; j2 < K2; ++j2)
            relBT[(size_t)(b * 12 + e) * K2 + j2] = 0;
    }

    // pfB tail: betas, ones (vtemp hi/lo), zero pad
#pragma unroll
    for (int l = 0; l < NBETA; ++l)
        pfB[(size_t)b * KP + PF + l] = f2bf(bet[l]);
    pfB[(size_t)b * KP + PF + NBETA]     = 0x3F80;
    pfB[(size_t)b * KP + PF + NBETA + 1] = 0x3F80;
    for (int k = PF + NBETA + 2; k < KP; ++k) pfB[(size_t)b * KP + k] = 0;
}

// ---------------------------------------------------------------------------
// k_main v3: barrier-free, wave-autonomous. Block = 64 verts x (NBT x 16)
// batches, 256 thr. Wave w owns vertices 16w..16w+15:
//   GEMM1: its 48 v3-rows x 16 batches -> xls[w] (private region)
//   GEMM2: all 192 be x its 16 vertices -> Tls[w] (private region)
//   Epilogue: lane (lr,hi2) handles vertex lr, batches hi2+4q.
// No __syncthreads: every LDS read is of the same wave's writes (lgkmcnt).
// ---------------------------------------------------------------------------
__global__ __launch_bounds__(256, 4) void k_main(
    const unsigned short* __restrict__ pdT,    // (V3PAD, KP)
    const unsigned short* __restrict__ pfB,    // (BB, KP)
    const unsigned short* __restrict__ lbswB,  // (VPAD, K2)
    const unsigned short* __restrict__ relBT,  // (BB*12, K2)
    float* __restrict__ verts)                 // (B,V,3)
{
    int btg = blockIdx.x;           // batch-tile group 0..15
    int vt  = blockIdx.y;           // vert tile 0..107
    int t   = threadIdx.x;
    int lane = t & 63;
    int w    = t >> 6;

    __shared__ float xls[4][48 * XSW];            // 13056 B
    __shared__ unsigned short Tls[4][16 * TSW];   // 25600 B

    int lr  = lane & 15;
    int hi2 = lane >> 4;
    int lk  = hi2 * 8;

    // wave-invariant operands
    const unsigned short* pa = pdT + (size_t)(vt * M3 + w * 48 + lr) * KP + lk;
    s16x8 lf = *(const s16x8*)(lbswB + (size_t)(vt * VTB + w * 16 + lr) * K2 + lk);

    int vglob = vt * VTB + w * 16 + lr;
    bool vok = vglob < VV;
    float* xw = &xls[w][0];
    unsigned short* Tw = &Tls[w][0];

    for (int it = 0; it < NBT; ++it) {
        int b0 = (btg * NBT + it) * 16;

        // ---- GEMM1: x rows 48w..48w+47, all 16 batches ----
        {
            f32x4 acc[3];
#pragma unroll
            for (int s = 0; s < 3; ++s) acc[s] = (f32x4){0.f,0.f,0.f,0.f};
            const unsigned short* pb = pfB + (size_t)(b0 + lr) * KP + lk;
#pragma unroll
            for (int ks = 0; ks < KP / 32; ++ks) {
                s16x8 bf = *(const s16x8*)(pb + ks * 32);
#pragma unroll
                for (int s = 0; s < 3; ++s) {
                    s16x8 a = *(const s16x8*)(pa + (size_t)(s * 16) * KP + ks * 32);
                    acc[s] = __builtin_amdgcn_mfma_f32_16x16x32_bf16(a, bf, acc[s], 0, 0, 0);
                }
            }
            // D: col(lr)=batch, row(hi2*4+r)=v3-sub -> xls[w][(v3local)*XSW + b]
#pragma unroll
            for (int s = 0; s < 3; ++s)
#pragma unroll
                for (int r = 0; r < 4; ++r)
                    xw[(s * 16 + hi2 * 4 + r) * XSW + lr] = acc[s][r];
        }

        // ---- GEMM2: all 192 be for wave's 16 vertices ----
        {
#pragma unroll
            for (int mt = 0; mt < 12; ++mt) {
                s16x8 rf = *(const s16x8*)(relBT +
                    (size_t)(b0 * 12 + mt * 16 + lr) * K2 + lk);
                f32x4 a2 = {0.f,0.f,0.f,0.f};
                a2 = __builtin_amdgcn_mfma_f32_16x16x32_bf16(rf, lf, a2, 0, 0, 0);
                // D: col(lr)=v-sub, row(hi2*4+r)=be-sub -> Tls[w][v*TSW + be]
                union { s16x4 v4; unsigned short u[4]; } pk;
#pragma unroll
                for (int r = 0; r < 4; ++r) pk.u[r] = f2bf(a2[r]);
                *(s16x4*)&Tw[lr * TSW + mt * 16 + hi2 * 4] = pk.v4;
            }
        }

        // ---- epilogue: vertex lr, batches hi2+4q (wave-local LDS only) ----
        if (vok) {
#pragma unroll
            for (int q = 0; q < 4; ++q) {
                int bl = hi2 + 4 * q;

                float x0 = xw[(3 * lr + 0) * XSW + bl];
                float x1 = xw[(3 * lr + 1) * XSW + bl];
                float x2 = xw[(3 * lr + 2) * XSW + bl];

                const unsigned short* tp = &Tw[lr * TSW + bl * 12];
                uint2 dA = *(const uint2*)tp;
                uint2 dB = *(const uint2*)(tp + 4);
                uint2 dC = *(const uint2*)(tp + 8);
                float T0  = __uint_as_float(dA.x << 16);
                float T1  = __uint_as_float(dA.x & 0xffff0000u);
                float T2  = __uint_as_float(dA.y << 16);
                float T3  = __uint_as_float(dA.y & 0xffff0000u);
                float T4  = __uint_as_float(dB.x << 16);
                float T5  = __uint_as_float(dB.x & 0xffff0000u);
                float T6  = __uint_as_float(dB.y << 16);
                float T7  = __uint_as_float(dB.y & 0xffff0000u);
                float T8  = __uint_as_float(dC.x << 16);
                float T9  = __uint_as_float(dC.x & 0xffff0000u);
                float T10 = __uint_as_float(dC.y << 16);
                float T11 = __uint_as_float(dC.y & 0xffff0000u);

                float o0 = T0 * x0 + T1 * x1 + T2  * x2 + T3;
                float o1 = T4 * x0 + T5 * x1 + T6  * x2 + T7;
                float o2 = T8 * x0 + T9 * x1 + T10 * x2 + T11;

                float* o = verts + ((size_t)(b0 + bl) * VV + vglob) * 3;
                o[0] = o0; o[1] = o1; o[2] = o2;
            }
        }
    }
}

extern "C" void kernel_launch(void* const* d_in, const int* in_sizes, int n_in,
                              void* d_out, int out_size, void* d_ws, size_t ws_size,
                              hipStream_t stream) {
    const float* transl = (const float*)d_in[0];
    const float* orient = (const float*)d_in[1];
    const float* betas  = (const float*)d_in[2];
    const float* bpose  = (const float*)d_in[3];
    const float* vtemp  = (const float*)d_in[4];
    const float* sdirs  = (const float*)d_in[5];
    const float* pdirs  = (const float*)d_in[6];
    const float* jreg   = (const float*)d_in[7];
    const float* lbsw   = (const float*)d_in[8];

    float* out = (float*)d_out;
    float* verts_out  = out;
    float* joints_out = out + (size_t)BB * VV * 3;

    float* ws    = (float*)d_ws;
    float* jpart = ws;                                   // 6336 f
    unsigned short* pfB   = (unsigned short*)(ws + 6336);      // B*KP
    unsigned short* pdT   = pfB + (size_t)BB * KP;             // V3PAD*KP
    unsigned short* lbswB = pdT + (size_t)V3PAD * KP;          // VPAD*K2
    unsigned short* relBT = lbswB + (size_t)VPAD * K2;         // B*12*K2

    k_prep_all<<<NBLK_A + NBLK_B + NBLK_C, 256, 0, stream>>>(
        pdirs, sdirs, vtemp, lbsw, jreg, pdT, lbswB, jpart);
    k_batch<<<BB / 32, 32, 0, stream>>>(transl, orient, betas, bpose,
                                        jpart, pfB, relBT, joints_out);
    dim3 g(BB / 16 / NBT, NVT);
    k_main<<<g, 256, 0, stream>>>(pdT, pfB, lbswB, relBT, verts_out);
}